// Round 2
// baseline (450.181 us; speedup 1.0000x reference)
//
#include <hip/hip_runtime.h>
#include <hip/hip_bf16.h>

typedef __hip_bfloat16 bf16;

#define DEV static __device__ __forceinline__

DEV float b2f(bf16 x) { return __bfloat162float(x); }
// generic load: isb=1 -> buffer is bf16, else f32
DEV float ldf(const void* p, long i, int isb) {
  return isb ? b2f(((const bf16*)p)[i]) : ((const float*)p)[i];
}
DEV void stf(void* p, long i, float v, int isb) {
  if (isb) ((bf16*)p)[i] = __float2bfloat16(v);
  else     ((float*)p)[i] = v;
}

// ---- problem constants ----
#define N_ATOMS 2500
#define N_EDGES 40000

constexpr int cK[4]    = {128, 96, 64, 32};     // KMAX
constexpr int cPL[4]   = {0, 2, 2, 4};          // padded L per l
constexpr int cLO[4]   = {96, 64, 32, 0};       // channel slice lower bound per l
constexpr int cSOFF[4] = {0, 32, 320, 608};     // section offset in 1408-float atom row
constexpr int cROFF[4] = {0, 128, 224, 288};    // radial row offset (320 floats/edge)
// ws float-offsets (weights converted to f32 by k_prep)
constexpr int cWR1[4] = {0, 512, 896, 1152};
constexpr int cWR2[4] = {1280, 9472, 15616, 19712};
constexpr int cWL[4]  = {21760, 38144, 47360, 51456};
constexpr int cUOF[4] = {52480, 52481, 52481, 52562}; // U[PL[idx]] base
constexpr int FLAG_OFF = 53240;                 // dtype flag (in the 53187..53247 gap)
constexpr int RAD_OFF  = 53248;
constexpr int UNC_OFF  = RAD_OFF + N_EDGES * 320;   // 12,853,248
constexpr int POOL_OFF = UNC_OFF + N_ATOMS * 1408;  // 16,373,248

constexpr int cCB[4]  = {0, 128, 416, 736};     // concat LDS base per l (x32 floats)
constexpr int cOUT[4] = {0, 320000, 1040000, 1840000};

// k_out combo tables: combo -> (l, mm, s), ordered so LDS addr = combo*32+k
__device__ const int c_tl[30]  = {0,0,0,0, 1,1,1,1,1,1,1,1,1, 2,2,2,2,2,2,2,2,2,2, 3,3,3,3,3,3,3};
__device__ const int c_tmm[30] = {0,0,0,0, 0,0,0,1,1,1,2,2,2, 0,0,1,1,2,2,3,3,4,4, 0,1,2,3,4,5,6};
__device__ const int c_ts[30]  = {0,1,2,3, 0,1,2,0,1,2,0,1,2, 0,1,0,1,0,1,0,1,0,1, 0,0,0,0,0,0,0};
__device__ const int c_soff_r[4] = {0, 32, 320, 608};
__device__ const int c_uof_r[4]  = {52480, 52481, 52481, 52562};
__device__ const int c_pl_r[4]   = {0, 2, 2, 4};

// ---------------- k_detect: decide f32 vs bf16 from Wr2_0's low halves ----------------
// If the buffer holds real bf16 values (~N(0,1)*0.1), the low 16 bits of each
// 32-bit word are a plausible bf16 (exponent ~110..130). If it holds f32, the
// low 16 bits are random mantissa bits -> exponent uniform -> ~16% in-window.
__global__ void k_detect(const void* __restrict__ w2_0, int* __restrict__ flag) {
  if (threadIdx.x != 0 || blockIdx.x != 0) return;
  const unsigned* w = (const unsigned*)w2_0;
  int ok = 0;
  for (int i = 0; i < 512; ++i) {
    unsigned lo = w[i] & 0xFFFFu;
    unsigned e = (lo >> 7) & 0xFFu;
    if (lo == 0u || (e >= 100u && e <= 140u)) ok++;
  }
  *flag = (ok >= 256) ? 1 : 0;
}

// ---------------- k_prep: weights/U (either dtype) -> f32 in ws ----------------
__global__ __launch_bounds__(256) void k_prep(
    const void* __restrict__ w10, const void* __restrict__ w11, const void* __restrict__ w12, const void* __restrict__ w13,
    const void* __restrict__ w20, const void* __restrict__ w21, const void* __restrict__ w22, const void* __restrict__ w23,
    const void* __restrict__ wl0, const void* __restrict__ wl1, const void* __restrict__ wl2, const void* __restrict__ wl3,
    const void* __restrict__ u0, const void* __restrict__ u2, const void* __restrict__ u4,
    const int* __restrict__ flag, float* __restrict__ ws) {
  int i = blockIdx.x * 256 + threadIdx.x;
  if (i >= 53187) return;
  int isb = *flag;
  const void* src; int base;
  if      (i < 512)   { src = w10; base = 0; }
  else if (i < 896)   { src = w11; base = 512; }
  else if (i < 1152)  { src = w12; base = 896; }
  else if (i < 1280)  { src = w13; base = 1152; }
  else if (i < 9472)  { src = w20; base = 1280; }
  else if (i < 15616) { src = w21; base = 9472; }
  else if (i < 19712) { src = w22; base = 15616; }
  else if (i < 21760) { src = w23; base = 19712; }
  else if (i < 38144) { src = wl0; base = 21760; }
  else if (i < 47360) { src = wl1; base = 38144; }
  else if (i < 51456) { src = wl2; base = 47360; }
  else if (i < 52480) { src = wl3; base = 51456; }
  else if (i < 52481) { src = u0;  base = 52480; }
  else if (i < 52562) { src = u2;  base = 52481; }
  else                { src = u4;  base = 52562; }
  ws[i] = ldf(src, i - base, isb);
}

// ---------------- k_radial: per-edge MLP, radial[e][320] f32 ----------------
template <int NM, int K>
DEV void radial_one(const void* __restrict__ rb, const float* __restrict__ Wr1f,
                    const float* __restrict__ Wr2f, float* __restrict__ outp, int e, int isb) {
  float rbv[NM];
#pragma unroll
  for (int n = 0; n < NM; ++n) rbv[n] = ldf(rb, (long)e * NM + n, isb);
  float acc[K];
#pragma unroll
  for (int c = 0; c < K; ++c) acc[c] = 0.f;
  for (int j = 0; j < 64; ++j) {
    float a = 0.f;
#pragma unroll
    for (int n = 0; n < NM; ++n) a += rbv[n] * Wr1f[n * 64 + j];
    float hj = a * (1.0f / (1.0f + __expf(-a)));   // silu
    const float* w = Wr2f + j * K;
#pragma unroll
    for (int c = 0; c < K; ++c) acc[c] += hj * w[c];
  }
#pragma unroll
  for (int c = 0; c < K; c += 4) {
    float4 v = make_float4(acc[c], acc[c + 1], acc[c + 2], acc[c + 3]);
    *reinterpret_cast<float4*>(outp + c) = v;
  }
}

__global__ __launch_bounds__(256) void k_radial(
    const void* __restrict__ rb0, const void* __restrict__ rb1,
    const void* __restrict__ rb2, const void* __restrict__ rb3,
    const int* __restrict__ flag, const float* __restrict__ ws, float* __restrict__ rad) {
  int e = blockIdx.x * 256 + threadIdx.x;
  if (e >= N_EDGES) return;
  int isb = *flag;
  float* rrow = rad + (size_t)e * 320;
  radial_one<8, 128>(rb0, ws + cWR1[0], ws + cWR2[0], rrow + cROFF[0], e, isb);
  radial_one<6,  96>(rb1, ws + cWR1[1], ws + cWR2[1], rrow + cROFF[1], e, isb);
  radial_one<4,  64>(rb2, ws + cWR1[2], ws + cWR2[2], rrow + cROFF[2], e, isb);
  radial_one<2,  32>(rb3, ws + cWR1[3], ws + cWR2[3], rrow + cROFF[3], e, isb);
}

// ---------------- k_uncfeat: per-atom uncoupled features ----------------
template <int l>
DEV void unc_one(int a, int k,
                 const void* __restrict__ f0, const void* __restrict__ f1,
                 const void* __restrict__ f2, const void* __restrict__ f3,
                 const float* __restrict__ ws, float* __restrict__ dst, int isb) {
  constexpr int T = cPL[l] + 1;
  constexpr int T2 = T * T;
  constexpr int M = (l + 1) * (l + 1);
  const float* U = ws + cUOF[l];
  const void* fps[4] = {f0, f1, f2, f3};
  float fc[M];
#pragma unroll
  for (int lp = 0; lp <= l; ++lp) {
    const void* fp = fps[lp];
#pragma unroll
    for (int mm = 0; mm < 2 * lp + 1; ++mm)
      fc[lp * lp + mm] = ldf(fp, ((long)a * (2 * lp + 1) + mm) * cK[lp] + cLO[l] + k, isb);
  }
#pragma unroll
  for (int q = 0; q < T2; ++q) {
    float s = 0.f;
#pragma unroll
    for (int m = 0; m < M; ++m) s += U[q * T2 + m] * fc[m];
    dst[cSOFF[l] + q * 32 + k] = s;
  }
}

__global__ __launch_bounds__(64) void k_uncfeat(
    const void* __restrict__ f0, const void* __restrict__ f1,
    const void* __restrict__ f2, const void* __restrict__ f3,
    const int* __restrict__ flag, const float* __restrict__ ws, float* __restrict__ unc) {
  int a = blockIdx.x * 2 + (threadIdx.x >> 5);
  int k = threadIdx.x & 31;
  if (a >= N_ATOMS) return;
  int isb = *flag;
  float* dst = unc + (size_t)a * 1408;
  unc_one<0>(a, k, f0, f1, f2, f3, ws, dst, isb);
  unc_one<1>(a, k, f0, f1, f2, f3, ws, dst, isb);
  unc_one<2>(a, k, f0, f1, f2, f3, ws, dst, isb);
  unc_one<3>(a, k, f0, f1, f2, f3, ws, dst, isb);
}

// ---------------- k_edge: uncouple vec, gather, matmul, scatter-add ----------------
template <int l>
DEV void edge_one(int e, int k, const float* __restrict__ rrow,
                  const void* __restrict__ s0, const void* __restrict__ s1,
                  const void* __restrict__ s2, const void* __restrict__ s3,
                  const float* __restrict__ ws, const float* __restrict__ frow,
                  float* __restrict__ prow, int isb) {
  constexpr int T = cPL[l] + 1;
  constexpr int T2 = T * T;
  constexpr int M = (l + 1) * (l + 1);
  const float* U = ws + cUOF[l];
  const void* sps[4] = {s0, s1, s2, s3};
  float vc[M];
#pragma unroll
  for (int lp = 0; lp <= l; ++lp) {
    float rv = rrow[cROFF[lp] + cLO[l] + k];
    const void* sp = sps[lp];
#pragma unroll
    for (int mm = 0; mm < 2 * lp + 1; ++mm)
      vc[lp * lp + mm] = ldf(sp, (long)e * (2 * lp + 1) + mm, isb) * rv;
  }
  float V[T2];
#pragma unroll
  for (int q = 0; q < T2; ++q) {
    float s = 0.f;
#pragma unroll
    for (int m = 0; m < M; ++m) s += U[q * T2 + m] * vc[m];
    V[q] = s;
  }
  float F[T2];
#pragma unroll
  for (int q = 0; q < T2; ++q) F[q] = frow[cSOFF[l] + q * 32 + k];
#pragma unroll
  for (int i = 0; i < T; ++i) {
#pragma unroll
    for (int j = 0; j < T; ++j) {
      float c = 0.f;
#pragma unroll
      for (int t = 0; t < T; ++t) c += V[i * T + t] * F[t * T + j];
      atomicAdd(prow + cSOFF[l] + (i * T + j) * 32 + k, c);
    }
  }
}

__global__ __launch_bounds__(64) void k_edge(
    const void* __restrict__ s0, const void* __restrict__ s1,
    const void* __restrict__ s2, const void* __restrict__ s3,
    const int* __restrict__ centers, const int* __restrict__ neighbors,
    const int* __restrict__ flag, const float* __restrict__ ws,
    const float* __restrict__ rad, const float* __restrict__ unc, float* __restrict__ pool) {
  int e = blockIdx.x * 2 + (threadIdx.x >> 5);
  int k = threadIdx.x & 31;
  if (e >= N_EDGES) return;
  int isb = *flag;
  int ce = centers[e], ne = neighbors[e];
  const float* rrow = rad + (size_t)e * 320;
  const float* frow = unc + (size_t)ne * 1408;
  float* prow = pool + (size_t)ce * 1408;
  edge_one<0>(e, k, rrow, s0, s1, s2, s3, ws, frow, prow, isb);
  edge_one<1>(e, k, rrow, s0, s1, s2, s3, ws, frow, prow, isb);
  edge_one<2>(e, k, rrow, s0, s1, s2, s3, ws, frow, prow, isb);
  edge_one<3>(e, k, rrow, s0, s1, s2, s3, ws, frow, prow, isb);
}

// ---------------- k_out: couple + concat + Wl + residual ----------------
template <int l>
DEV void out_one(int a0, const float* __restrict__ ws,
                 const float* __restrict__ cc0, const float* __restrict__ cc1,
                 const void* __restrict__ fp, void* __restrict__ out, int isb) {
  constexpr int K = cK[l];
  constexpr int NMM = 2 * l + 1;
  constexpr int NS = 4 - l;
  const float* Wl = ws + cWL[l];
  for (int oc = threadIdx.x; oc < NMM * K; oc += 128) {
    int mm = oc / K, cp = oc % K;
    const float* p0 = cc0 + cCB[l] + mm * NS * 32;
    const float* p1 = cc1 + cCB[l] + mm * NS * 32;
    float acc0 = 0.f, acc1 = 0.f;
#pragma unroll 4
    for (int c = 0; c < K; ++c) {
      float w = Wl[c * K + cp];
      acc0 += w * p0[c];
      acc1 += w * p1[c];
    }
    long b0 = ((long)a0 * NMM + mm) * K + cp;
    long b1 = ((long)(a0 + 1) * NMM + mm) * K + cp;
    stf(out, cOUT[l] + b0, ldf(fp, b0, isb) + acc0, isb);
    stf(out, cOUT[l] + b1, ldf(fp, b1, isb) + acc1, isb);
  }
}

__global__ __launch_bounds__(128) void k_out(
    const void* __restrict__ f0, const void* __restrict__ f1,
    const void* __restrict__ f2, const void* __restrict__ f3,
    const int* __restrict__ flag, const float* __restrict__ ws, void* __restrict__ out) {
  __shared__ float cc[2][960];
  int half = threadIdx.x >> 6;
  int t = threadIdx.x & 63;
  int a = blockIdx.x * 2 + half;
  int isb = *flag;
  const float* pool = ws + POOL_OFF + (size_t)a * 1408;
  for (int idx = t; idx < 960; idx += 64) {
    int k = idx & 31, combo = idx >> 5;
    int l = c_tl[combo], mm = c_tmm[combo], s = c_ts[combo];
    int lp = l + s;
    int Ts = c_pl_r[lp] + 1;
    int Ts2 = Ts * Ts;
    const float* U = ws + c_uof_r[lp];
    const float* pr = pool + c_soff_r[lp];
    int m = l * l + mm;
    float sacc = 0.f;
    for (int q = 0; q < Ts2; ++q) sacc += U[q * Ts2 + m] * pr[q * 32 + k];
    cc[half][idx] = sacc;
  }
  __syncthreads();
  int a0 = blockIdx.x * 2;
  out_one<0>(a0, ws, cc[0], cc[1], f0, out, isb);
  out_one<1>(a0, ws, cc[0], cc[1], f1, out, isb);
  out_one<2>(a0, ws, cc[0], cc[1], f2, out, isb);
  out_one<3>(a0, ws, cc[0], cc[1], f3, out, isb);
}

// ---------------- launch ----------------
extern "C" void kernel_launch(void* const* d_in, const int* in_sizes, int n_in,
                              void* d_out, int out_size, void* d_ws, size_t ws_size,
                              hipStream_t stream) {
  (void)n_in; (void)out_size; (void)ws_size;
  // ---- input order detection (host-side, deterministic) ----
  // dict order:  rb0,sph0,ft0, rb1,sph1,ft1, ... -> in_sizes[1] = 40000 (sph0)
  // sig  order:  rb0..rb3, sph0..sph3, ft0..ft3  -> in_sizes[1] = 240000 (rb1)
  bool dictord = (in_sizes[1] == 40000);
  const void* rb[4]; const void* sph[4]; const void* ft[4];
  const void *w1[4], *w2[4], *wl[4];
  for (int l = 0; l < 4; ++l) {
    if (dictord) {
      rb[l]  = d_in[3 * l + 0];
      sph[l] = d_in[3 * l + 1];
      ft[l]  = d_in[3 * l + 2];
      w1[l]  = d_in[17 + 3 * l];
      w2[l]  = d_in[18 + 3 * l];
      wl[l]  = d_in[19 + 3 * l];
    } else {
      rb[l]  = d_in[l];
      sph[l] = d_in[4 + l];
      ft[l]  = d_in[8 + l];
      w1[l]  = d_in[17 + l];
      w2[l]  = d_in[21 + l];
      wl[l]  = d_in[25 + l];
    }
  }
  const int* centers   = (const int*)d_in[12];
  const int* neighbors = (const int*)d_in[13];
  const void* u0 = d_in[14];
  const void* u2 = d_in[15];
  const void* u4 = d_in[16];

  float* ws   = (float*)d_ws;
  int*   flag = (int*)(ws + FLAG_OFF);
  float* rad  = ws + RAD_OFF;
  float* unc  = ws + UNC_OFF;
  float* pool = ws + POOL_OFF;

  hipMemsetAsync(pool, 0, (size_t)N_ATOMS * 1408 * sizeof(float), stream);
  k_detect<<<1, 64, 0, stream>>>(w2[0], flag);
  k_prep<<<208, 256, 0, stream>>>(w1[0], w1[1], w1[2], w1[3],
                                  w2[0], w2[1], w2[2], w2[3],
                                  wl[0], wl[1], wl[2], wl[3],
                                  u0, u2, u4, flag, ws);
  k_radial<<<(N_EDGES + 255) / 256, 256, 0, stream>>>(rb[0], rb[1], rb[2], rb[3], flag, ws, rad);
  k_uncfeat<<<N_ATOMS / 2, 64, 0, stream>>>(ft[0], ft[1], ft[2], ft[3], flag, ws, unc);
  k_edge<<<N_EDGES / 2, 64, 0, stream>>>(sph[0], sph[1], sph[2], sph[3],
                                         centers, neighbors, flag, ws, rad, unc, pool);
  k_out<<<N_ATOMS / 2, 128, 0, stream>>>(ft[0], ft[1], ft[2], ft[3], flag, ws, (void*)d_out);
}

// Round 3
// 370.367 us; speedup vs baseline: 1.2155x; 1.2155x over previous
//
#include <hip/hip_runtime.h>
#include <hip/hip_bf16.h>

typedef __hip_bfloat16 bf16;

#define DEV static __device__ __forceinline__

DEV float b2f(bf16 x) { return __bfloat162float(x); }
// generic load: isb=1 -> buffer is bf16, else f32
DEV float ldf(const void* p, long i, int isb) {
  return isb ? b2f(((const bf16*)p)[i]) : ((const float*)p)[i];
}
DEV void stf(void* p, long i, float v, int isb) {
  if (isb) ((bf16*)p)[i] = __float2bfloat16(v);
  else     ((float*)p)[i] = v;
}

// ---- problem constants ----
#define N_ATOMS 2500
#define N_EDGES 40000

constexpr int cK[4]    = {128, 96, 64, 32};     // KMAX
constexpr int cPL[4]   = {0, 2, 2, 4};          // padded L per l
constexpr int cLO[4]   = {96, 64, 32, 0};       // channel slice lower bound per l
constexpr int cSOFF[4] = {0, 32, 320, 608};     // section offset in 1408-float atom row
constexpr int cROFF[4] = {0, 128, 224, 288};    // radial row offset (320 floats/edge)
constexpr int cAOF[4]  = {0, 1, 10, 19};        // acc-register offset per l (total 44)
// ws float-offsets (weights converted to f32 by k_prep)
constexpr int cWR1[4] = {0, 512, 896, 1152};
constexpr int cWR2[4] = {1280, 9472, 15616, 19712};
constexpr int cWL[4]  = {21760, 38144, 47360, 51456};
constexpr int cUOF[4] = {52480, 52481, 52481, 52562}; // U[PL[idx]] base
constexpr int FLAG_OFF = 53240;                 // dtype flag (in the 53187..53247 gap)
constexpr int RAD_OFF  = 53248;
constexpr int UNC_OFF  = RAD_OFF + N_EDGES * 320;   // 12,853,248
constexpr int POOL_OFF = UNC_OFF + N_ATOMS * 1408;  // 16,373,248
// CSR area (ints) after pool
constexpr int CSR_OFF   = POOL_OFF + N_ATOMS * 1408; // 19,893,248
constexpr int CNT_OFF   = CSR_OFF;                   // [2500]
constexpr int START_OFF = CSR_OFF + 2500;            // [2501]
constexpr int FILL_OFF  = CSR_OFF + 5008;            // [2500]
constexpr int ELIST_OFF = CSR_OFF + 7512;            // [40000]

constexpr int cCB[4]  = {0, 128, 416, 736};     // concat LDS base per l (x32 floats)
constexpr int cOUT[4] = {0, 320000, 1040000, 1840000};

// k_out combo tables: combo -> (l, mm, s), ordered so LDS addr = combo*32+k
__device__ const int c_tl[30]  = {0,0,0,0, 1,1,1,1,1,1,1,1,1, 2,2,2,2,2,2,2,2,2,2, 3,3,3,3,3,3,3};
__device__ const int c_tmm[30] = {0,0,0,0, 0,0,0,1,1,1,2,2,2, 0,0,1,1,2,2,3,3,4,4, 0,1,2,3,4,5,6};
__device__ const int c_ts[30]  = {0,1,2,3, 0,1,2,0,1,2,0,1,2, 0,1,0,1,0,1,0,1,0,1, 0,0,0,0,0,0,0};
__device__ const int c_soff_r[4] = {0, 32, 320, 608};
__device__ const int c_uof_r[4]  = {52480, 52481, 52481, 52562};
__device__ const int c_pl_r[4]   = {0, 2, 2, 4};

// ---------------- k_detect: decide f32 vs bf16 from Wr2_0's low halves ----------------
__global__ void k_detect(const void* __restrict__ w2_0, int* __restrict__ flag) {
  if (threadIdx.x != 0 || blockIdx.x != 0) return;
  const unsigned* w = (const unsigned*)w2_0;
  int ok = 0;
  for (int i = 0; i < 512; ++i) {
    unsigned lo = w[i] & 0xFFFFu;
    unsigned e = (lo >> 7) & 0xFFu;
    if (lo == 0u || (e >= 100u && e <= 140u)) ok++;
  }
  *flag = (ok >= 256) ? 1 : 0;
}

// ---------------- k_prep: weights/U (either dtype) -> f32 in ws ----------------
__global__ __launch_bounds__(256) void k_prep(
    const void* __restrict__ w10, const void* __restrict__ w11, const void* __restrict__ w12, const void* __restrict__ w13,
    const void* __restrict__ w20, const void* __restrict__ w21, const void* __restrict__ w22, const void* __restrict__ w23,
    const void* __restrict__ wl0, const void* __restrict__ wl1, const void* __restrict__ wl2, const void* __restrict__ wl3,
    const void* __restrict__ u0, const void* __restrict__ u2, const void* __restrict__ u4,
    const int* __restrict__ flag, float* __restrict__ ws) {
  int i = blockIdx.x * 256 + threadIdx.x;
  if (i >= 53187) return;
  int isb = *flag;
  const void* src; int base;
  if      (i < 512)   { src = w10; base = 0; }
  else if (i < 896)   { src = w11; base = 512; }
  else if (i < 1152)  { src = w12; base = 896; }
  else if (i < 1280)  { src = w13; base = 1152; }
  else if (i < 9472)  { src = w20; base = 1280; }
  else if (i < 15616) { src = w21; base = 9472; }
  else if (i < 19712) { src = w22; base = 15616; }
  else if (i < 21760) { src = w23; base = 19712; }
  else if (i < 38144) { src = wl0; base = 21760; }
  else if (i < 47360) { src = wl1; base = 38144; }
  else if (i < 51456) { src = wl2; base = 47360; }
  else if (i < 52480) { src = wl3; base = 51456; }
  else if (i < 52481) { src = u0;  base = 52480; }
  else if (i < 52562) { src = u2;  base = 52481; }
  else                { src = u4;  base = 52562; }
  ws[i] = ldf(src, i - base, isb);
}

// ---------------- CSR build: count / scan / fill ----------------
__global__ __launch_bounds__(256) void k_count(const int* __restrict__ centers, int* __restrict__ cnt) {
  int e = blockIdx.x * 256 + threadIdx.x;
  if (e < N_EDGES) atomicAdd(&cnt[centers[e]], 1);
}

__global__ __launch_bounds__(256) void k_scan(const int* __restrict__ cnt,
                                              int* __restrict__ start, int* __restrict__ fill) {
  __shared__ int part[256];
  int t = threadIdx.x;
  int loc[10];
  int s = 0;
  int base = t * 10;
#pragma unroll
  for (int i = 0; i < 10; ++i) {
    int c = (base + i < N_ATOMS) ? cnt[base + i] : 0;
    loc[i] = s; s += c;
  }
  part[t] = s;
  __syncthreads();
  // Hillis-Steele inclusive scan over 256 partials
  for (int off = 1; off < 256; off <<= 1) {
    int v = part[t];
    if (t >= off) v += part[t - off];
    __syncthreads();
    part[t] = v;
    __syncthreads();
  }
  int excl = (t == 0) ? 0 : part[t - 1];
#pragma unroll
  for (int i = 0; i < 10; ++i) {
    if (base + i < N_ATOMS) {
      start[base + i] = excl + loc[i];
      fill[base + i]  = excl + loc[i];
    }
  }
  if (t == 255) start[N_ATOMS] = part[255];
}

__global__ __launch_bounds__(256) void k_fill(const int* __restrict__ centers,
                                              int* __restrict__ fill, int* __restrict__ elist) {
  int e = blockIdx.x * 256 + threadIdx.x;
  if (e >= N_EDGES) return;
  int pos = atomicAdd(&fill[centers[e]], 1);
  elist[pos] = e;
}

// ---------------- k_radial: per-edge MLP, radial[e][320] f32 ----------------
template <int NM, int K>
DEV void radial_one(const void* __restrict__ rb, const float* __restrict__ Wr1f,
                    const float* __restrict__ Wr2f, float* __restrict__ outp, int e, int isb) {
  float rbv[NM];
#pragma unroll
  for (int n = 0; n < NM; ++n) rbv[n] = ldf(rb, (long)e * NM + n, isb);
  float acc[K];
#pragma unroll
  for (int c = 0; c < K; ++c) acc[c] = 0.f;
  for (int j = 0; j < 64; ++j) {
    float a = 0.f;
#pragma unroll
    for (int n = 0; n < NM; ++n) a += rbv[n] * Wr1f[n * 64 + j];
    float hj = a * (1.0f / (1.0f + __expf(-a)));   // silu
    const float* w = Wr2f + j * K;
#pragma unroll
    for (int c = 0; c < K; ++c) acc[c] += hj * w[c];
  }
#pragma unroll
  for (int c = 0; c < K; c += 4) {
    float4 v = make_float4(acc[c], acc[c + 1], acc[c + 2], acc[c + 3]);
    *reinterpret_cast<float4*>(outp + c) = v;
  }
}

__global__ __launch_bounds__(256) void k_radial(
    const void* __restrict__ rb0, const void* __restrict__ rb1,
    const void* __restrict__ rb2, const void* __restrict__ rb3,
    const int* __restrict__ flag, const float* __restrict__ ws, float* __restrict__ rad) {
  int e = blockIdx.x * 256 + threadIdx.x;
  if (e >= N_EDGES) return;
  int isb = *flag;
  float* rrow = rad + (size_t)e * 320;
  radial_one<8, 128>(rb0, ws + cWR1[0], ws + cWR2[0], rrow + cROFF[0], e, isb);
  radial_one<6,  96>(rb1, ws + cWR1[1], ws + cWR2[1], rrow + cROFF[1], e, isb);
  radial_one<4,  64>(rb2, ws + cWR1[2], ws + cWR2[2], rrow + cROFF[2], e, isb);
  radial_one<2,  32>(rb3, ws + cWR1[3], ws + cWR2[3], rrow + cROFF[3], e, isb);
}

// ---------------- k_uncfeat: per-atom uncoupled features ----------------
template <int l>
DEV void unc_one(int a, int k,
                 const void* __restrict__ f0, const void* __restrict__ f1,
                 const void* __restrict__ f2, const void* __restrict__ f3,
                 const float* __restrict__ ws, float* __restrict__ dst, int isb) {
  constexpr int T = cPL[l] + 1;
  constexpr int T2 = T * T;
  constexpr int M = (l + 1) * (l + 1);
  const float* U = ws + cUOF[l];
  const void* fps[4] = {f0, f1, f2, f3};
  float fc[M];
#pragma unroll
  for (int lp = 0; lp <= l; ++lp) {
    const void* fp = fps[lp];
#pragma unroll
    for (int mm = 0; mm < 2 * lp + 1; ++mm)
      fc[lp * lp + mm] = ldf(fp, ((long)a * (2 * lp + 1) + mm) * cK[lp] + cLO[l] + k, isb);
  }
#pragma unroll
  for (int q = 0; q < T2; ++q) {
    float s = 0.f;
#pragma unroll
    for (int m = 0; m < M; ++m) s += U[q * T2 + m] * fc[m];
    dst[cSOFF[l] + q * 32 + k] = s;
  }
}

__global__ __launch_bounds__(64) void k_uncfeat(
    const void* __restrict__ f0, const void* __restrict__ f1,
    const void* __restrict__ f2, const void* __restrict__ f3,
    const int* __restrict__ flag, const float* __restrict__ ws, float* __restrict__ unc) {
  int a = blockIdx.x * 2 + (threadIdx.x >> 5);
  int k = threadIdx.x & 31;
  if (a >= N_ATOMS) return;
  int isb = *flag;
  float* dst = unc + (size_t)a * 1408;
  unc_one<0>(a, k, f0, f1, f2, f3, ws, dst, isb);
  unc_one<1>(a, k, f0, f1, f2, f3, ws, dst, isb);
  unc_one<2>(a, k, f0, f1, f2, f3, ws, dst, isb);
  unc_one<3>(a, k, f0, f1, f2, f3, ws, dst, isb);
}

// ---------------- k_edge2: CSR per-atom accumulation, no atomics ----------------
template <int l>
DEV void edge_acc(int e, int k, const float* __restrict__ rrow,
                  const void* __restrict__ s0, const void* __restrict__ s1,
                  const void* __restrict__ s2, const void* __restrict__ s3,
                  const float* __restrict__ ws, const float* __restrict__ frow,
                  float* __restrict__ accl, int isb) {
  constexpr int T = cPL[l] + 1;
  constexpr int T2 = T * T;
  constexpr int M = (l + 1) * (l + 1);
  const float* U = ws + cUOF[l];
  const void* sps[4] = {s0, s1, s2, s3};
  float vc[M];
#pragma unroll
  for (int lp = 0; lp <= l; ++lp) {
    float rv = rrow[cROFF[lp] + cLO[l] + k];
    const void* sp = sps[lp];
#pragma unroll
    for (int mm = 0; mm < 2 * lp + 1; ++mm)
      vc[lp * lp + mm] = ldf(sp, (long)e * (2 * lp + 1) + mm, isb) * rv;
  }
  float V[T2];
#pragma unroll
  for (int q = 0; q < T2; ++q) {
    float s = 0.f;
#pragma unroll
    for (int m = 0; m < M; ++m) s += U[q * T2 + m] * vc[m];
    V[q] = s;
  }
  float F[T2];
#pragma unroll
  for (int q = 0; q < T2; ++q) F[q] = frow[cSOFF[l] + q * 32 + k];
#pragma unroll
  for (int i = 0; i < T; ++i) {
#pragma unroll
    for (int j = 0; j < T; ++j) {
      float c = 0.f;
#pragma unroll
      for (int t = 0; t < T; ++t) c += V[i * T + t] * F[t * T + j];
      accl[i * T + j] += c;
    }
  }
}

__global__ __launch_bounds__(128) void k_edge2(
    const void* __restrict__ s0, const void* __restrict__ s1,
    const void* __restrict__ s2, const void* __restrict__ s3,
    const int* __restrict__ start, const int* __restrict__ elist,
    const int* __restrict__ neighbors, const int* __restrict__ flag,
    const float* __restrict__ ws, const float* __restrict__ rad,
    const float* __restrict__ unc, float* __restrict__ pool) {
  int a = blockIdx.x;
  int tid = threadIdx.x;
  int w = tid >> 6;            // wave 0/1
  int k = tid & 31;            // channel
  int strm = (tid >> 5) & 3;   // 4 edge streams (wave*2 + half)
  int isb = *flag;
  int beg = start[a], end = start[a + 1];

  float acc[44];
#pragma unroll
  for (int j = 0; j < 44; ++j) acc[j] = 0.f;

  for (int i = beg + strm; i < end; i += 4) {
    int e = elist[i];
    int ne = neighbors[e];
    const float* rrow = rad + (size_t)e * 320;
    const float* frow = unc + (size_t)ne * 1408;
    edge_acc<0>(e, k, rrow, s0, s1, s2, s3, ws, frow, acc + cAOF[0], isb);
    edge_acc<1>(e, k, rrow, s0, s1, s2, s3, ws, frow, acc + cAOF[1], isb);
    edge_acc<2>(e, k, rrow, s0, s1, s2, s3, ws, frow, acc + cAOF[2], isb);
    edge_acc<3>(e, k, rrow, s0, s1, s2, s3, ws, frow, acc + cAOF[3], isb);
  }
  // combine the two half-waves of each wave
#pragma unroll
  for (int j = 0; j < 44; ++j) acc[j] += __shfl_xor(acc[j], 32);

  __shared__ float buf[2][1408];
  if ((tid & 32) == 0) {  // lanes 0-31 of each wave hold the wave's sums
#pragma unroll
    for (int l = 0; l < 4; ++l) {
      int T2 = (cPL[l] + 1) * (cPL[l] + 1);
      for (int q = 0; q < T2; ++q)
        buf[w][cSOFF[l] + q * 32 + k] = acc[cAOF[l] + q];
    }
  }
  __syncthreads();
  float* prow = pool + (size_t)a * 1408;
  for (int idx = tid; idx < 1408; idx += 128)
    prow[idx] = buf[0][idx] + buf[1][idx];
}

// ---------------- k_out: couple + concat + Wl + residual ----------------
template <int l>
DEV void out_one(int a0, const float* __restrict__ ws,
                 const float* __restrict__ cc0, const float* __restrict__ cc1,
                 const void* __restrict__ fp, void* __restrict__ out, int isb) {
  constexpr int K = cK[l];
  constexpr int NMM = 2 * l + 1;
  constexpr int NS = 4 - l;
  const float* Wl = ws + cWL[l];
  for (int oc = threadIdx.x; oc < NMM * K; oc += 128) {
    int mm = oc / K, cp = oc % K;
    const float* p0 = cc0 + cCB[l] + mm * NS * 32;
    const float* p1 = cc1 + cCB[l] + mm * NS * 32;
    float acc0 = 0.f, acc1 = 0.f;
#pragma unroll 4
    for (int c = 0; c < K; ++c) {
      float w = Wl[c * K + cp];
      acc0 += w * p0[c];
      acc1 += w * p1[c];
    }
    long b0 = ((long)a0 * NMM + mm) * K + cp;
    long b1 = ((long)(a0 + 1) * NMM + mm) * K + cp;
    stf(out, cOUT[l] + b0, ldf(fp, b0, isb) + acc0, isb);
    stf(out, cOUT[l] + b1, ldf(fp, b1, isb) + acc1, isb);
  }
}

__global__ __launch_bounds__(128) void k_out(
    const void* __restrict__ f0, const void* __restrict__ f1,
    const void* __restrict__ f2, const void* __restrict__ f3,
    const int* __restrict__ flag, const float* __restrict__ ws, void* __restrict__ out) {
  __shared__ float cc[2][960];
  int half = threadIdx.x >> 6;
  int t = threadIdx.x & 63;
  int a = blockIdx.x * 2 + half;
  int isb = *flag;
  const float* pool = ws + POOL_OFF + (size_t)a * 1408;
  for (int idx = t; idx < 960; idx += 64) {
    int k = idx & 31, combo = idx >> 5;
    int l = c_tl[combo], mm = c_tmm[combo], s = c_ts[combo];
    int lp = l + s;
    int Ts = c_pl_r[lp] + 1;
    int Ts2 = Ts * Ts;
    const float* U = ws + c_uof_r[lp];
    const float* pr = pool + c_soff_r[lp];
    int m = l * l + mm;
    float sacc = 0.f;
    for (int q = 0; q < Ts2; ++q) sacc += U[q * Ts2 + m] * pr[q * 32 + k];
    cc[half][idx] = sacc;
  }
  __syncthreads();
  int a0 = blockIdx.x * 2;
  out_one<0>(a0, ws, cc[0], cc[1], f0, out, isb);
  out_one<1>(a0, ws, cc[0], cc[1], f1, out, isb);
  out_one<2>(a0, ws, cc[0], cc[1], f2, out, isb);
  out_one<3>(a0, ws, cc[0], cc[1], f3, out, isb);
}

// ---------------- launch ----------------
extern "C" void kernel_launch(void* const* d_in, const int* in_sizes, int n_in,
                              void* d_out, int out_size, void* d_ws, size_t ws_size,
                              hipStream_t stream) {
  (void)n_in; (void)out_size; (void)ws_size;
  bool dictord = (in_sizes[1] == 40000);
  const void* rb[4]; const void* sph[4]; const void* ft[4];
  const void *w1[4], *w2[4], *wl[4];
  for (int l = 0; l < 4; ++l) {
    if (dictord) {
      rb[l]  = d_in[3 * l + 0];
      sph[l] = d_in[3 * l + 1];
      ft[l]  = d_in[3 * l + 2];
      w1[l]  = d_in[17 + 3 * l];
      w2[l]  = d_in[18 + 3 * l];
      wl[l]  = d_in[19 + 3 * l];
    } else {
      rb[l]  = d_in[l];
      sph[l] = d_in[4 + l];
      ft[l]  = d_in[8 + l];
      w1[l]  = d_in[17 + l];
      w2[l]  = d_in[21 + l];
      wl[l]  = d_in[25 + l];
    }
  }
  const int* centers   = (const int*)d_in[12];
  const int* neighbors = (const int*)d_in[13];
  const void* u0 = d_in[14];
  const void* u2 = d_in[15];
  const void* u4 = d_in[16];

  float* ws   = (float*)d_ws;
  int*   flag = (int*)(ws + FLAG_OFF);
  float* rad  = ws + RAD_OFF;
  float* unc  = ws + UNC_OFF;
  float* pool = ws + POOL_OFF;
  int*   cnt   = (int*)(ws + CNT_OFF);
  int*   start = (int*)(ws + START_OFF);
  int*   fill  = (int*)(ws + FILL_OFF);
  int*   elist = (int*)(ws + ELIST_OFF);

  hipMemsetAsync(cnt, 0, N_ATOMS * sizeof(int), stream);
  k_detect<<<1, 64, 0, stream>>>(w2[0], flag);
  k_count<<<(N_EDGES + 255) / 256, 256, 0, stream>>>(centers, cnt);
  k_scan<<<1, 256, 0, stream>>>(cnt, start, fill);
  k_fill<<<(N_EDGES + 255) / 256, 256, 0, stream>>>(centers, fill, elist);
  k_prep<<<208, 256, 0, stream>>>(w1[0], w1[1], w1[2], w1[3],
                                  w2[0], w2[1], w2[2], w2[3],
                                  wl[0], wl[1], wl[2], wl[3],
                                  u0, u2, u4, flag, ws);
  k_radial<<<(N_EDGES + 255) / 256, 256, 0, stream>>>(rb[0], rb[1], rb[2], rb[3], flag, ws, rad);
  k_uncfeat<<<N_ATOMS / 2, 64, 0, stream>>>(ft[0], ft[1], ft[2], ft[3], flag, ws, unc);
  k_edge2<<<N_ATOMS, 128, 0, stream>>>(sph[0], sph[1], sph[2], sph[3],
                                       start, elist, neighbors, flag, ws, rad, unc, pool);
  k_out<<<N_ATOMS / 2, 128, 0, stream>>>(ft[0], ft[1], ft[2], ft[3], flag, ws, (void*)d_out);
}

// Round 4
// 366.588 us; speedup vs baseline: 1.2280x; 1.0103x over previous
//
#include <hip/hip_runtime.h>
#include <hip/hip_bf16.h>

typedef __hip_bfloat16 bf16;

#define DEV static __device__ __forceinline__

DEV float b2f(bf16 x) { return __bfloat162float(x); }
// generic load: isb=1 -> buffer is bf16, else f32
DEV float ldf(const void* p, long i, int isb) {
  return isb ? b2f(((const bf16*)p)[i]) : ((const float*)p)[i];
}
DEV void stf(void* p, long i, float v, int isb) {
  if (isb) ((bf16*)p)[i] = __float2bfloat16(v);
  else     ((float*)p)[i] = v;
}

// ---- problem constants ----
#define N_ATOMS 2500
#define N_EDGES 40000

constexpr int cK[4]    = {128, 96, 64, 32};     // KMAX
constexpr int cPL[4]   = {0, 2, 2, 4};          // padded L per l
constexpr int cLO[4]   = {96, 64, 32, 0};       // channel slice lower bound per l
constexpr int cSOFF[4] = {0, 32, 320, 608};     // section offset in 1408-float atom row
constexpr int cROFF[4] = {0, 128, 224, 288};    // radial row offset (320 floats/edge)
constexpr int cAOF[4]  = {0, 1, 10, 19};        // acc-register offset per l (total 44)
// ws float-offsets (weights converted to f32 by k_prep)
constexpr int cWR1[4] = {0, 512, 896, 1152};
constexpr int cWR2[4] = {1280, 9472, 15616, 19712};
constexpr int cWL[4]  = {21760, 38144, 47360, 51456};
constexpr int cUOF[4] = {52480, 52481, 52481, 52562}; // U[PL[idx]] base
constexpr int FLAG_OFF = 53240;                 // dtype flag (in the 53187..53247 gap)
constexpr int RAD_OFF  = 53248;
constexpr int UNC_OFF  = RAD_OFF + N_EDGES * 320;   // 12,853,248
constexpr int POOL_OFF = UNC_OFF + N_ATOMS * 1408;  // 16,373,248
// CSR area (ints) after pool
constexpr int CSR_OFF   = POOL_OFF + N_ATOMS * 1408; // 19,893,248
constexpr int CNT_OFF   = CSR_OFF;                   // [2500]
constexpr int START_OFF = CSR_OFF + 2500;            // [2501]
constexpr int FILL_OFF  = CSR_OFF + 5008;            // [2500]
constexpr int ELIST_OFF = CSR_OFF + 7512;            // [40000]

constexpr int cCB[4]  = {0, 128, 416, 736};     // concat LDS base per l (x32 floats)
constexpr int cOUT[4] = {0, 320000, 1040000, 1840000};

// k_out combo tables: combo -> (l, mm, s), ordered so LDS addr = combo*32+k
__device__ const int c_tl[30]  = {0,0,0,0, 1,1,1,1,1,1,1,1,1, 2,2,2,2,2,2,2,2,2,2, 3,3,3,3,3,3,3};
__device__ const int c_tmm[30] = {0,0,0,0, 0,0,0,1,1,1,2,2,2, 0,0,1,1,2,2,3,3,4,4, 0,1,2,3,4,5,6};
__device__ const int c_ts[30]  = {0,1,2,3, 0,1,2,0,1,2,0,1,2, 0,1,0,1,0,1,0,1,0,1, 0,0,0,0,0,0,0};
__device__ const int c_soff_r[4] = {0, 32, 320, 608};
__device__ const int c_uof_r[4]  = {52480, 52481, 52481, 52562};
__device__ const int c_pl_r[4]   = {0, 2, 2, 4};
// radial chunk tables: 10 chunks of 32 channels
__device__ const int chk_l[10]  = {0,0,0,0, 1,1,1, 2,2, 3};
__device__ const int chk_c0[10] = {0,32,64,96, 0,32,64, 0,32, 0};

// ---------------- k_detect: decide f32 vs bf16 from Wr2_0's low halves ----------------
__global__ void k_detect(const void* __restrict__ w2_0, int* __restrict__ flag) {
  if (threadIdx.x != 0 || blockIdx.x != 0) return;
  const unsigned* w = (const unsigned*)w2_0;
  int ok = 0;
  for (int i = 0; i < 512; ++i) {
    unsigned lo = w[i] & 0xFFFFu;
    unsigned e = (lo >> 7) & 0xFFu;
    if (lo == 0u || (e >= 100u && e <= 140u)) ok++;
  }
  *flag = (ok >= 256) ? 1 : 0;
}

// ---------------- k_prep: weights/U (either dtype) -> f32 in ws ----------------
__global__ __launch_bounds__(256) void k_prep(
    const void* __restrict__ w10, const void* __restrict__ w11, const void* __restrict__ w12, const void* __restrict__ w13,
    const void* __restrict__ w20, const void* __restrict__ w21, const void* __restrict__ w22, const void* __restrict__ w23,
    const void* __restrict__ wl0, const void* __restrict__ wl1, const void* __restrict__ wl2, const void* __restrict__ wl3,
    const void* __restrict__ u0, const void* __restrict__ u2, const void* __restrict__ u4,
    const int* __restrict__ flag, float* __restrict__ ws) {
  int i = blockIdx.x * 256 + threadIdx.x;
  if (i >= 53187) return;
  int isb = *flag;
  const void* src; int base;
  if      (i < 512)   { src = w10; base = 0; }
  else if (i < 896)   { src = w11; base = 512; }
  else if (i < 1152)  { src = w12; base = 896; }
  else if (i < 1280)  { src = w13; base = 1152; }
  else if (i < 9472)  { src = w20; base = 1280; }
  else if (i < 15616) { src = w21; base = 9472; }
  else if (i < 19712) { src = w22; base = 15616; }
  else if (i < 21760) { src = w23; base = 19712; }
  else if (i < 38144) { src = wl0; base = 21760; }
  else if (i < 47360) { src = wl1; base = 38144; }
  else if (i < 51456) { src = wl2; base = 47360; }
  else if (i < 52480) { src = wl3; base = 51456; }
  else if (i < 52481) { src = u0;  base = 52480; }
  else if (i < 52562) { src = u2;  base = 52481; }
  else                { src = u4;  base = 52562; }
  ws[i] = ldf(src, i - base, isb);
}

// ---------------- CSR build: count / scan / fill ----------------
__global__ __launch_bounds__(256) void k_count(const int* __restrict__ centers, int* __restrict__ cnt) {
  int e = blockIdx.x * 256 + threadIdx.x;
  if (e < N_EDGES) atomicAdd(&cnt[centers[e]], 1);
}

__global__ __launch_bounds__(256) void k_scan(const int* __restrict__ cnt,
                                              int* __restrict__ start, int* __restrict__ fill) {
  __shared__ int part[256];
  int t = threadIdx.x;
  int loc[10];
  int s = 0;
  int base = t * 10;
#pragma unroll
  for (int i = 0; i < 10; ++i) {
    int c = (base + i < N_ATOMS) ? cnt[base + i] : 0;
    loc[i] = s; s += c;
  }
  part[t] = s;
  __syncthreads();
  for (int off = 1; off < 256; off <<= 1) {
    int v = part[t];
    if (t >= off) v += part[t - off];
    __syncthreads();
    part[t] = v;
    __syncthreads();
  }
  int excl = (t == 0) ? 0 : part[t - 1];
#pragma unroll
  for (int i = 0; i < 10; ++i) {
    if (base + i < N_ATOMS) {
      start[base + i] = excl + loc[i];
      fill[base + i]  = excl + loc[i];
    }
  }
  if (t == 255) start[N_ATOMS] = part[255];
}

__global__ __launch_bounds__(256) void k_fill(const int* __restrict__ centers,
                                              int* __restrict__ fill, int* __restrict__ elist) {
  int e = blockIdx.x * 256 + threadIdx.x;
  if (e >= N_EDGES) return;
  int pos = atomicAdd(&fill[centers[e]], 1);
  elist[pos] = e;
}

// ---------------- k_radial2: per-(edge,chunk) MLP, 32 channels/thread ----------------
template <int NM, int K>
DEV void radial_chunk(const void* __restrict__ rb, const float* __restrict__ Wr1f,
                      const float* __restrict__ Wr2f, float* __restrict__ outp,
                      int e, int c0, int isb) {
  float rbv[NM];
#pragma unroll
  for (int n = 0; n < NM; ++n) rbv[n] = ldf(rb, (long)e * NM + n, isb);
  float acc[32];
#pragma unroll
  for (int c = 0; c < 32; ++c) acc[c] = 0.f;
  for (int j = 0; j < 64; ++j) {
    float a = 0.f;
#pragma unroll
    for (int n = 0; n < NM; ++n) a += rbv[n] * Wr1f[n * 64 + j];
    float hj = a * (1.0f / (1.0f + __expf(-a)));   // silu
    const float* w = Wr2f + j * K + c0;
#pragma unroll
    for (int c = 0; c < 32; ++c) acc[c] += hj * w[c];
  }
#pragma unroll
  for (int c = 0; c < 32; c += 4) {
    float4 v = make_float4(acc[c], acc[c + 1], acc[c + 2], acc[c + 3]);
    *reinterpret_cast<float4*>(outp + c0 + c) = v;
  }
}

__global__ __launch_bounds__(256) void k_radial2(
    const void* __restrict__ rb0, const void* __restrict__ rb1,
    const void* __restrict__ rb2, const void* __restrict__ rb3,
    const int* __restrict__ flag, const float* __restrict__ ws, float* __restrict__ rad) {
  int g = blockIdx.x * 256 + threadIdx.x;
  if (g >= N_EDGES * 10) return;
  int isb = *flag;
  int chunk = g / N_EDGES;
  int e = g - chunk * N_EDGES;
  int l = chk_l[chunk], c0 = chk_c0[chunk];
  float* rrow = rad + (size_t)e * 320;
  switch (l) {
    case 0: radial_chunk<8, 128>(rb0, ws + cWR1[0], ws + cWR2[0], rrow + cROFF[0], e, c0, isb); break;
    case 1: radial_chunk<6,  96>(rb1, ws + cWR1[1], ws + cWR2[1], rrow + cROFF[1], e, c0, isb); break;
    case 2: radial_chunk<4,  64>(rb2, ws + cWR1[2], ws + cWR2[2], rrow + cROFF[2], e, c0, isb); break;
    default: radial_chunk<2, 32>(rb3, ws + cWR1[3], ws + cWR2[3], rrow + cROFF[3], e, c0, isb); break;
  }
}

// ---------------- k_uncfeat: per-atom uncoupled features ----------------
template <int l>
DEV void unc_one(int a, int k,
                 const void* __restrict__ f0, const void* __restrict__ f1,
                 const void* __restrict__ f2, const void* __restrict__ f3,
                 const float* __restrict__ ws, float* __restrict__ dst, int isb) {
  constexpr int T = cPL[l] + 1;
  constexpr int T2 = T * T;
  constexpr int M = (l + 1) * (l + 1);
  const float* U = ws + cUOF[l];
  const void* fps[4] = {f0, f1, f2, f3};
  float fc[M];
#pragma unroll
  for (int lp = 0; lp <= l; ++lp) {
    const void* fp = fps[lp];
#pragma unroll
    for (int mm = 0; mm < 2 * lp + 1; ++mm)
      fc[lp * lp + mm] = ldf(fp, ((long)a * (2 * lp + 1) + mm) * cK[lp] + cLO[l] + k, isb);
  }
#pragma unroll
  for (int q = 0; q < T2; ++q) {
    float s = 0.f;
#pragma unroll
    for (int m = 0; m < M; ++m) s += U[q * T2 + m] * fc[m];
    dst[cSOFF[l] + q * 32 + k] = s;
  }
}

__global__ __launch_bounds__(64) void k_uncfeat(
    const void* __restrict__ f0, const void* __restrict__ f1,
    const void* __restrict__ f2, const void* __restrict__ f3,
    const int* __restrict__ flag, const float* __restrict__ ws, float* __restrict__ unc) {
  int a = blockIdx.x * 2 + (threadIdx.x >> 5);
  int k = threadIdx.x & 31;
  if (a >= N_ATOMS) return;
  int isb = *flag;
  float* dst = unc + (size_t)a * 1408;
  unc_one<0>(a, k, f0, f1, f2, f3, ws, dst, isb);
  unc_one<1>(a, k, f0, f1, f2, f3, ws, dst, isb);
  unc_one<2>(a, k, f0, f1, f2, f3, ws, dst, isb);
  unc_one<3>(a, k, f0, f1, f2, f3, ws, dst, isb);
}

// ---------------- k_edge2: CSR per-atom accumulation, no atomics ----------------
template <int l>
DEV void edge_acc(int e, int k, const float* __restrict__ rrow,
                  const void* __restrict__ s0, const void* __restrict__ s1,
                  const void* __restrict__ s2, const void* __restrict__ s3,
                  const float* __restrict__ ws, const float* __restrict__ frow,
                  float* __restrict__ accl, int isb) {
  constexpr int T = cPL[l] + 1;
  constexpr int T2 = T * T;
  constexpr int M = (l + 1) * (l + 1);
  const float* U = ws + cUOF[l];
  const void* sps[4] = {s0, s1, s2, s3};
  float vc[M];
#pragma unroll
  for (int lp = 0; lp <= l; ++lp) {
    float rv = rrow[cROFF[lp] + cLO[l] + k];
    const void* sp = sps[lp];
#pragma unroll
    for (int mm = 0; mm < 2 * lp + 1; ++mm)
      vc[lp * lp + mm] = ldf(sp, (long)e * (2 * lp + 1) + mm, isb) * rv;
  }
  float V[T2];
#pragma unroll
  for (int q = 0; q < T2; ++q) {
    float s = 0.f;
#pragma unroll
    for (int m = 0; m < M; ++m) s += U[q * T2 + m] * vc[m];
    V[q] = s;
  }
  float F[T2];
#pragma unroll
  for (int q = 0; q < T2; ++q) F[q] = frow[cSOFF[l] + q * 32 + k];
#pragma unroll
  for (int i = 0; i < T; ++i) {
#pragma unroll
    for (int j = 0; j < T; ++j) {
      float c = 0.f;
#pragma unroll
      for (int t = 0; t < T; ++t) c += V[i * T + t] * F[t * T + j];
      accl[i * T + j] += c;
    }
  }
}

__global__ __launch_bounds__(256) void k_edge2(
    const void* __restrict__ s0, const void* __restrict__ s1,
    const void* __restrict__ s2, const void* __restrict__ s3,
    const int* __restrict__ start, const int* __restrict__ elist,
    const int* __restrict__ neighbors, const int* __restrict__ flag,
    const float* __restrict__ ws, const float* __restrict__ rad,
    const float* __restrict__ unc, float* __restrict__ pool) {
  int a = blockIdx.x;
  int tid = threadIdx.x;
  int wv = tid >> 6;           // wave 0..3
  int k = tid & 31;            // channel
  int strm = tid >> 5;         // 8 edge streams (wave*2 + half)
  int isb = *flag;
  int beg = start[a], end = start[a + 1];

  float acc[44];
#pragma unroll
  for (int j = 0; j < 44; ++j) acc[j] = 0.f;

  for (int i = beg + strm; i < end; i += 8) {
    int e = elist[i];
    int ne = neighbors[e];
    const float* rrow = rad + (size_t)e * 320;
    const float* frow = unc + (size_t)ne * 1408;
    edge_acc<0>(e, k, rrow, s0, s1, s2, s3, ws, frow, acc + cAOF[0], isb);
    edge_acc<1>(e, k, rrow, s0, s1, s2, s3, ws, frow, acc + cAOF[1], isb);
    edge_acc<2>(e, k, rrow, s0, s1, s2, s3, ws, frow, acc + cAOF[2], isb);
    edge_acc<3>(e, k, rrow, s0, s1, s2, s3, ws, frow, acc + cAOF[3], isb);
  }
  // combine the two half-waves of each wave
#pragma unroll
  for (int j = 0; j < 44; ++j) acc[j] += __shfl_xor(acc[j], 32);

  __shared__ float buf[4][1408];
  if ((tid & 32) == 0) {  // lanes 0-31 of each wave hold the wave's sums
#pragma unroll
    for (int l = 0; l < 4; ++l) {
      int T2 = (cPL[l] + 1) * (cPL[l] + 1);
      for (int q = 0; q < T2; ++q)
        buf[wv][cSOFF[l] + q * 32 + k] = acc[cAOF[l] + q];
    }
  }
  __syncthreads();
  float* prow = pool + (size_t)a * 1408;
  for (int idx = tid; idx < 1408; idx += 256)
    prow[idx] = (buf[0][idx] + buf[1][idx]) + (buf[2][idx] + buf[3][idx]);
}

// ---------------- k_out: couple + concat + Wl + residual ----------------
template <int l>
DEV void out_one(int a0, const float* __restrict__ ws,
                 const float* __restrict__ cc0, const float* __restrict__ cc1,
                 const void* __restrict__ fp, void* __restrict__ out, int isb) {
  constexpr int K = cK[l];
  constexpr int NMM = 2 * l + 1;
  constexpr int NS = 4 - l;
  const float* Wl = ws + cWL[l];
  for (int oc = threadIdx.x; oc < NMM * K; oc += 128) {
    int mm = oc / K, cp = oc % K;
    const float* p0 = cc0 + cCB[l] + mm * NS * 32;
    const float* p1 = cc1 + cCB[l] + mm * NS * 32;
    float acc0 = 0.f, acc1 = 0.f;
#pragma unroll 4
    for (int c = 0; c < K; ++c) {
      float w = Wl[c * K + cp];
      acc0 += w * p0[c];
      acc1 += w * p1[c];
    }
    long b0 = ((long)a0 * NMM + mm) * K + cp;
    long b1 = ((long)(a0 + 1) * NMM + mm) * K + cp;
    stf(out, cOUT[l] + b0, ldf(fp, b0, isb) + acc0, isb);
    stf(out, cOUT[l] + b1, ldf(fp, b1, isb) + acc1, isb);
  }
}

__global__ __launch_bounds__(128) void k_out(
    const void* __restrict__ f0, const void* __restrict__ f1,
    const void* __restrict__ f2, const void* __restrict__ f3,
    const int* __restrict__ flag, const float* __restrict__ ws, void* __restrict__ out) {
  __shared__ float cc[2][960];
  int half = threadIdx.x >> 6;
  int t = threadIdx.x & 63;
  int a = blockIdx.x * 2 + half;
  int isb = *flag;
  const float* pool = ws + POOL_OFF + (size_t)a * 1408;
  for (int idx = t; idx < 960; idx += 64) {
    int k = idx & 31, combo = idx >> 5;
    int l = c_tl[combo], mm = c_tmm[combo], s = c_ts[combo];
    int lp = l + s;
    int Ts = c_pl_r[lp] + 1;
    int Ts2 = Ts * Ts;
    const float* U = ws + c_uof_r[lp];
    const float* pr = pool + c_soff_r[lp];
    int m = l * l + mm;
    float sacc = 0.f;
    for (int q = 0; q < Ts2; ++q) sacc += U[q * Ts2 + m] * pr[q * 32 + k];
    cc[half][idx] = sacc;
  }
  __syncthreads();
  int a0 = blockIdx.x * 2;
  out_one<0>(a0, ws, cc[0], cc[1], f0, out, isb);
  out_one<1>(a0, ws, cc[0], cc[1], f1, out, isb);
  out_one<2>(a0, ws, cc[0], cc[1], f2, out, isb);
  out_one<3>(a0, ws, cc[0], cc[1], f3, out, isb);
}

// ---------------- launch ----------------
extern "C" void kernel_launch(void* const* d_in, const int* in_sizes, int n_in,
                              void* d_out, int out_size, void* d_ws, size_t ws_size,
                              hipStream_t stream) {
  (void)n_in; (void)out_size; (void)ws_size;
  bool dictord = (in_sizes[1] == 40000);
  const void* rb[4]; const void* sph[4]; const void* ft[4];
  const void *w1[4], *w2[4], *wl[4];
  for (int l = 0; l < 4; ++l) {
    if (dictord) {
      rb[l]  = d_in[3 * l + 0];
      sph[l] = d_in[3 * l + 1];
      ft[l]  = d_in[3 * l + 2];
      w1[l]  = d_in[17 + 3 * l];
      w2[l]  = d_in[18 + 3 * l];
      wl[l]  = d_in[19 + 3 * l];
    } else {
      rb[l]  = d_in[l];
      sph[l] = d_in[4 + l];
      ft[l]  = d_in[8 + l];
      w1[l]  = d_in[17 + l];
      w2[l]  = d_in[21 + l];
      wl[l]  = d_in[25 + l];
    }
  }
  const int* centers   = (const int*)d_in[12];
  const int* neighbors = (const int*)d_in[13];
  const void* u0 = d_in[14];
  const void* u2 = d_in[15];
  const void* u4 = d_in[16];

  float* ws   = (float*)d_ws;
  int*   flag = (int*)(ws + FLAG_OFF);
  float* rad  = ws + RAD_OFF;
  float* unc  = ws + UNC_OFF;
  float* pool = ws + POOL_OFF;
  int*   cnt   = (int*)(ws + CNT_OFF);
  int*   start = (int*)(ws + START_OFF);
  int*   fill  = (int*)(ws + FILL_OFF);
  int*   elist = (int*)(ws + ELIST_OFF);

  hipMemsetAsync(cnt, 0, N_ATOMS * sizeof(int), stream);
  k_detect<<<1, 64, 0, stream>>>(w2[0], flag);
  k_count<<<(N_EDGES + 255) / 256, 256, 0, stream>>>(centers, cnt);
  k_scan<<<1, 256, 0, stream>>>(cnt, start, fill);
  k_fill<<<(N_EDGES + 255) / 256, 256, 0, stream>>>(centers, fill, elist);
  k_prep<<<208, 256, 0, stream>>>(w1[0], w1[1], w1[2], w1[3],
                                  w2[0], w2[1], w2[2], w2[3],
                                  wl[0], wl[1], wl[2], wl[3],
                                  u0, u2, u4, flag, ws);
  k_radial2<<<(N_EDGES * 10 + 255) / 256, 256, 0, stream>>>(rb[0], rb[1], rb[2], rb[3], flag, ws, rad);
  k_uncfeat<<<N_ATOMS / 2, 64, 0, stream>>>(ft[0], ft[1], ft[2], ft[3], flag, ws, unc);
  k_edge2<<<N_ATOMS, 256, 0, stream>>>(sph[0], sph[1], sph[2], sph[3],
                                       start, elist, neighbors, flag, ws, rad, unc, pool);
  k_out<<<N_ATOMS / 2, 128, 0, stream>>>(ft[0], ft[1], ft[2], ft[3], flag, ws, (void*)d_out);
}

// Round 5
// 336.623 us; speedup vs baseline: 1.3373x; 1.0890x over previous
//
#include <hip/hip_runtime.h>
#include <hip/hip_bf16.h>

typedef __hip_bfloat16 bf16;

#define DEV static __device__ __forceinline__

DEV float b2f(bf16 x) { return __bfloat162float(x); }
// generic load: isb=1 -> buffer is bf16, else f32
DEV float ldf(const void* p, long i, int isb) {
  return isb ? b2f(((const bf16*)p)[i]) : ((const float*)p)[i];
}
DEV void stf(void* p, long i, float v, int isb) {
  if (isb) ((bf16*)p)[i] = __float2bfloat16(v);
  else     ((float*)p)[i] = v;
}

// ---- problem constants ----
#define N_ATOMS 2500
#define N_EDGES 40000

constexpr int cK[4]    = {128, 96, 64, 32};     // KMAX
constexpr int cPL[4]   = {0, 2, 2, 4};          // padded L per l
constexpr int cLO[4]   = {96, 64, 32, 0};       // channel slice lower bound per l
constexpr int cSOFF[4] = {0, 32, 320, 608};     // section offset in 1408-float atom row
constexpr int cROFF[4] = {0, 128, 224, 288};    // radial row offset (320 floats/edge)
constexpr int cAOF[4]  = {0, 1, 10, 19};        // acc-register offset per l (total 44)
// ws float-offsets (weights converted to f32 by k_prep)
constexpr int cWR1[4] = {0, 512, 896, 1152};
constexpr int cWR2[4] = {1280, 9472, 15616, 19712};
constexpr int cWL[4]  = {21760, 38144, 47360, 51456};
constexpr int cUOF[4] = {52480, 52481, 52481, 52562}; // U[PL[idx]] base
constexpr int FLAG_OFF = 53240;                 // dtype flag (in the 53187..53247 gap)
constexpr int RAD_OFF  = 53248;
constexpr int UNC_OFF  = RAD_OFF + N_EDGES * 320;   // 12,853,248
constexpr int POOL_OFF = UNC_OFF + N_ATOMS * 1408;  // 16,373,248
// CSR area (ints) after pool
constexpr int CSR_OFF   = POOL_OFF + N_ATOMS * 1408; // 19,893,248
constexpr int CNT_OFF   = CSR_OFF;                   // [2500]
constexpr int START_OFF = CSR_OFF + 2500;            // [2501]
constexpr int FILL_OFF  = CSR_OFF + 5008;            // [2500]
constexpr int ELIST_OFF = CSR_OFF + 7512;            // [40000]

constexpr int cCB[4]  = {0, 128, 416, 736};     // concat LDS base per l (x32 floats)
constexpr int cOUT[4] = {0, 320000, 1040000, 1840000};

// k_out combo tables: combo -> (l, mm, s), ordered so LDS addr = combo*32+k
__device__ const int c_tl[30]  = {0,0,0,0, 1,1,1,1,1,1,1,1,1, 2,2,2,2,2,2,2,2,2,2, 3,3,3,3,3,3,3};
__device__ const int c_tmm[30] = {0,0,0,0, 0,0,0,1,1,1,2,2,2, 0,0,1,1,2,2,3,3,4,4, 0,1,2,3,4,5,6};
__device__ const int c_ts[30]  = {0,1,2,3, 0,1,2,0,1,2,0,1,2, 0,1,0,1,0,1,0,1,0,1, 0,0,0,0,0,0,0};
__device__ const int c_soff_r[4] = {0, 32, 320, 608};
__device__ const int c_uof_r[4]  = {52480, 52481, 52481, 52562};
__device__ const int c_pl_r[4]   = {0, 2, 2, 4};
// radial chunk tables: 10 chunks of 32 channels
__device__ const int chk_l[10]  = {0,0,0,0, 1,1,1, 2,2, 3};
__device__ const int chk_c0[10] = {0,32,64,96, 0,32,64, 0,32, 0};

// ---------------- k_detect: decide f32 vs bf16 from Wr2_0's low halves ----------------
__global__ void k_detect(const void* __restrict__ w2_0, int* __restrict__ flag) {
  if (threadIdx.x != 0 || blockIdx.x != 0) return;
  const unsigned* w = (const unsigned*)w2_0;
  int ok = 0;
  for (int i = 0; i < 512; ++i) {
    unsigned lo = w[i] & 0xFFFFu;
    unsigned e = (lo >> 7) & 0xFFu;
    if (lo == 0u || (e >= 100u && e <= 140u)) ok++;
  }
  *flag = (ok >= 256) ? 1 : 0;
}

// ---------------- k_prep: weights/U (either dtype) -> f32 in ws ----------------
__global__ __launch_bounds__(256) void k_prep(
    const void* __restrict__ w10, const void* __restrict__ w11, const void* __restrict__ w12, const void* __restrict__ w13,
    const void* __restrict__ w20, const void* __restrict__ w21, const void* __restrict__ w22, const void* __restrict__ w23,
    const void* __restrict__ wl0, const void* __restrict__ wl1, const void* __restrict__ wl2, const void* __restrict__ wl3,
    const void* __restrict__ u0, const void* __restrict__ u2, const void* __restrict__ u4,
    const int* __restrict__ flag, float* __restrict__ ws) {
  int i = blockIdx.x * 256 + threadIdx.x;
  if (i >= 53187) return;
  int isb = *flag;
  const void* src; int base;
  if      (i < 512)   { src = w10; base = 0; }
  else if (i < 896)   { src = w11; base = 512; }
  else if (i < 1152)  { src = w12; base = 896; }
  else if (i < 1280)  { src = w13; base = 1152; }
  else if (i < 9472)  { src = w20; base = 1280; }
  else if (i < 15616) { src = w21; base = 9472; }
  else if (i < 19712) { src = w22; base = 15616; }
  else if (i < 21760) { src = w23; base = 19712; }
  else if (i < 38144) { src = wl0; base = 21760; }
  else if (i < 47360) { src = wl1; base = 38144; }
  else if (i < 51456) { src = wl2; base = 47360; }
  else if (i < 52480) { src = wl3; base = 51456; }
  else if (i < 52481) { src = u0;  base = 52480; }
  else if (i < 52562) { src = u2;  base = 52481; }
  else                { src = u4;  base = 52562; }
  ws[i] = ldf(src, i - base, isb);
}

// ---------------- CSR build: count / scan / fill ----------------
__global__ __launch_bounds__(256) void k_count(const int* __restrict__ centers, int* __restrict__ cnt) {
  int e = blockIdx.x * 256 + threadIdx.x;
  if (e < N_EDGES) atomicAdd(&cnt[centers[e]], 1);
}

__global__ __launch_bounds__(256) void k_scan(const int* __restrict__ cnt,
                                              int* __restrict__ start, int* __restrict__ fill) {
  __shared__ int part[256];
  int t = threadIdx.x;
  int loc[10];
  int s = 0;
  int base = t * 10;
#pragma unroll
  for (int i = 0; i < 10; ++i) {
    int c = (base + i < N_ATOMS) ? cnt[base + i] : 0;
    loc[i] = s; s += c;
  }
  part[t] = s;
  __syncthreads();
  for (int off = 1; off < 256; off <<= 1) {
    int v = part[t];
    if (t >= off) v += part[t - off];
    __syncthreads();
    part[t] = v;
    __syncthreads();
  }
  int excl = (t == 0) ? 0 : part[t - 1];
#pragma unroll
  for (int i = 0; i < 10; ++i) {
    if (base + i < N_ATOMS) {
      start[base + i] = excl + loc[i];
      fill[base + i]  = excl + loc[i];
    }
  }
  if (t == 255) start[N_ATOMS] = part[255];
}

__global__ __launch_bounds__(256) void k_fill(const int* __restrict__ centers,
                                              int* __restrict__ fill, int* __restrict__ elist) {
  int e = blockIdx.x * 256 + threadIdx.x;
  if (e >= N_EDGES) return;
  int pos = atomicAdd(&fill[centers[e]], 1);
  elist[pos] = e;
}

// ---------------- k_radial3: wave-uniform chunk, float4 weights, h in regs ----------------
template <int NM, int K>
DEV void radial_chunk3(const void* __restrict__ rb, const float* __restrict__ Wr1f,
                       const float* __restrict__ Wr2f, float* __restrict__ outp,
                       int e, int c0, int isb) {
  // phase 1: h[64] = silu(rb @ Wr1)
  float h[64];
#pragma unroll
  for (int j = 0; j < 64; ++j) h[j] = 0.f;
#pragma unroll
  for (int n = 0; n < NM; ++n) {
    float rv = ldf(rb, (long)e * NM + n, isb);
    const float4* wr = reinterpret_cast<const float4*>(Wr1f + n * 64);
#pragma unroll
    for (int j4 = 0; j4 < 16; ++j4) {
      float4 w = wr[j4];
      h[j4 * 4 + 0] += rv * w.x;
      h[j4 * 4 + 1] += rv * w.y;
      h[j4 * 4 + 2] += rv * w.z;
      h[j4 * 4 + 3] += rv * w.w;
    }
  }
#pragma unroll
  for (int j = 0; j < 64; ++j) {
    float a = h[j];
    h[j] = a * (1.0f / (1.0f + __expf(-a)));
  }
  // phase 2: acc[32] = h @ Wr2[:, c0:c0+32]
  float acc[32];
#pragma unroll
  for (int c = 0; c < 32; ++c) acc[c] = 0.f;
  for (int j = 0; j < 64; ++j) {
    float hj = h[j];
    const float4* w4 = reinterpret_cast<const float4*>(Wr2f + j * K + c0);
#pragma unroll
    for (int c4 = 0; c4 < 8; ++c4) {
      float4 w = w4[c4];
      acc[c4 * 4 + 0] += hj * w.x;
      acc[c4 * 4 + 1] += hj * w.y;
      acc[c4 * 4 + 2] += hj * w.z;
      acc[c4 * 4 + 3] += hj * w.w;
    }
  }
#pragma unroll
  for (int c = 0; c < 32; c += 4) {
    float4 v = make_float4(acc[c], acc[c + 1], acc[c + 2], acc[c + 3]);
    *reinterpret_cast<float4*>(outp + c0 + c) = v;
  }
}

__global__ __launch_bounds__(256) void k_radial3(
    const void* __restrict__ rb0, const void* __restrict__ rb1,
    const void* __restrict__ rb2, const void* __restrict__ rb3,
    const int* __restrict__ flag, const float* __restrict__ ws, float* __restrict__ rad) {
  int wave = (blockIdx.x * 256 + threadIdx.x) >> 6;  // global wave id
  int lane = threadIdx.x & 63;
  if (wave >= 6250) return;
  int isb = *flag;
  int chunk = wave / 625;                 // wave-uniform by construction
  chunk = __builtin_amdgcn_readfirstlane(chunk);
  int e = (wave - chunk * 625) * 64 + lane;
  int l = chk_l[chunk], c0 = chk_c0[chunk];
  float* rrow = rad + (size_t)e * 320;
  switch (l) {
    case 0: radial_chunk3<8, 128>(rb0, ws + cWR1[0], ws + cWR2[0], rrow + cROFF[0], e, c0, isb); break;
    case 1: radial_chunk3<6,  96>(rb1, ws + cWR1[1], ws + cWR2[1], rrow + cROFF[1], e, c0, isb); break;
    case 2: radial_chunk3<4,  64>(rb2, ws + cWR1[2], ws + cWR2[2], rrow + cROFF[2], e, c0, isb); break;
    default: radial_chunk3<2, 32>(rb3, ws + cWR1[3], ws + cWR2[3], rrow + cROFF[3], e, c0, isb); break;
  }
}

// ---------------- k_uncfeat: per-atom uncoupled features ----------------
template <int l>
DEV void unc_one(int a, int k,
                 const void* __restrict__ f0, const void* __restrict__ f1,
                 const void* __restrict__ f2, const void* __restrict__ f3,
                 const float* __restrict__ ws, float* __restrict__ dst, int isb) {
  constexpr int T = cPL[l] + 1;
  constexpr int T2 = T * T;
  constexpr int M = (l + 1) * (l + 1);
  const float* U = ws + cUOF[l];
  const void* fps[4] = {f0, f1, f2, f3};
  float fc[M];
#pragma unroll
  for (int lp = 0; lp <= l; ++lp) {
    const void* fp = fps[lp];
#pragma unroll
    for (int mm = 0; mm < 2 * lp + 1; ++mm)
      fc[lp * lp + mm] = ldf(fp, ((long)a * (2 * lp + 1) + mm) * cK[lp] + cLO[l] + k, isb);
  }
#pragma unroll
  for (int q = 0; q < T2; ++q) {
    float s = 0.f;
#pragma unroll
    for (int m = 0; m < M; ++m) s += U[q * T2 + m] * fc[m];
    dst[cSOFF[l] + q * 32 + k] = s;
  }
}

__global__ __launch_bounds__(64) void k_uncfeat(
    const void* __restrict__ f0, const void* __restrict__ f1,
    const void* __restrict__ f2, const void* __restrict__ f3,
    const int* __restrict__ flag, const float* __restrict__ ws, float* __restrict__ unc) {
  int a = blockIdx.x * 2 + (threadIdx.x >> 5);
  int k = threadIdx.x & 31;
  if (a >= N_ATOMS) return;
  int isb = *flag;
  float* dst = unc + (size_t)a * 1408;
  unc_one<0>(a, k, f0, f1, f2, f3, ws, dst, isb);
  unc_one<1>(a, k, f0, f1, f2, f3, ws, dst, isb);
  unc_one<2>(a, k, f0, f1, f2, f3, ws, dst, isb);
  unc_one<3>(a, k, f0, f1, f2, f3, ws, dst, isb);
}

// ---------------- k_edge3: CSR accumulation with S-factorized uncouple ----------------
// V[q](k) = sum_lp rv[lp](k) * S[q][lp],  S[q][lp] = sum_mm U[q, lp^2+mm]*sph[mm]
// S is k-independent: lane q computes it, others fetch via shfl within the 32-lane group.
template <int l>
DEV void edge_acc3(int e, int k, const float* __restrict__ rrow,
                   const void* __restrict__ s0, const void* __restrict__ s1,
                   const void* __restrict__ s2, const void* __restrict__ s3,
                   const float* __restrict__ ws, const float* __restrict__ frow,
                   float* __restrict__ accl, int isb) {
  constexpr int T = cPL[l] + 1;
  constexpr int T2 = T * T;
  const float* U = ws + cUOF[l];
  const void* sps[4] = {s0, s1, s2, s3};
  float rvl[l + 1];
#pragma unroll
  for (int lp = 0; lp <= l; ++lp) rvl[lp] = rrow[cROFF[lp] + cLO[l] + k];

  if constexpr (l == 0) {
    float S = U[0] * ldf(s0, e, isb);
    accl[0] += rvl[0] * S * frow[cSOFF[0] + k];
    return;
  }

  // phase A: lane q (=k) computes S[lp] for its q
  int qc = (k < T2) ? k : 0;
  float S[l + 1];
#pragma unroll
  for (int lp = 0; lp <= l; ++lp) {
    float s = 0.f;
    const void* sp = sps[lp];
#pragma unroll
    for (int mm = 0; mm < 2 * lp + 1; ++mm)
      s += U[qc * T2 + lp * lp + mm] * ldf(sp, (long)e * (2 * lp + 1) + mm, isb);
    S[lp] = s;
  }
  // phase B: every lane reconstructs V[q] via shfl broadcast
  float V[T2];
#pragma unroll
  for (int q = 0; q < T2; ++q) {
    float v = 0.f;
#pragma unroll
    for (int lp = 0; lp <= l; ++lp) v += rvl[lp] * __shfl(S[lp], q, 32);
    V[q] = v;
  }
  float F[T2];
#pragma unroll
  for (int q = 0; q < T2; ++q) F[q] = frow[cSOFF[l] + q * 32 + k];
#pragma unroll
  for (int i = 0; i < T; ++i) {
#pragma unroll
    for (int j = 0; j < T; ++j) {
      float c = 0.f;
#pragma unroll
      for (int t = 0; t < T; ++t) c += V[i * T + t] * F[t * T + j];
      accl[i * T + j] += c;
    }
  }
}

__global__ __launch_bounds__(256) void k_edge3(
    const void* __restrict__ s0, const void* __restrict__ s1,
    const void* __restrict__ s2, const void* __restrict__ s3,
    const int* __restrict__ start, const int* __restrict__ elist,
    const int* __restrict__ neighbors, const int* __restrict__ flag,
    const float* __restrict__ ws, const float* __restrict__ rad,
    const float* __restrict__ unc, float* __restrict__ pool) {
  int a = blockIdx.x;
  int tid = threadIdx.x;
  int wv = tid >> 6;           // wave 0..3
  int k = tid & 31;            // channel
  int strm = tid >> 5;         // 8 edge streams
  int isb = *flag;
  int beg = start[a], end = start[a + 1];

  float acc[44];
#pragma unroll
  for (int j = 0; j < 44; ++j) acc[j] = 0.f;

  for (int i = beg + strm; i < end; i += 8) {
    int e = elist[i];
    int ne = neighbors[e];
    const float* rrow = rad + (size_t)e * 320;
    const float* frow = unc + (size_t)ne * 1408;
    edge_acc3<0>(e, k, rrow, s0, s1, s2, s3, ws, frow, acc + cAOF[0], isb);
    edge_acc3<1>(e, k, rrow, s0, s1, s2, s3, ws, frow, acc + cAOF[1], isb);
    edge_acc3<2>(e, k, rrow, s0, s1, s2, s3, ws, frow, acc + cAOF[2], isb);
    edge_acc3<3>(e, k, rrow, s0, s1, s2, s3, ws, frow, acc + cAOF[3], isb);
  }
  // combine the two half-waves of each wave
#pragma unroll
  for (int j = 0; j < 44; ++j) acc[j] += __shfl_xor(acc[j], 32);

  __shared__ float buf[4][1408];
  if ((tid & 32) == 0) {  // lanes 0-31 of each wave hold the wave's sums
#pragma unroll
    for (int l = 0; l < 4; ++l) {
      int T2 = (cPL[l] + 1) * (cPL[l] + 1);
      for (int q = 0; q < T2; ++q)
        buf[wv][cSOFF[l] + q * 32 + k] = acc[cAOF[l] + q];
    }
  }
  __syncthreads();
  float* prow = pool + (size_t)a * 1408;
  for (int idx = tid; idx < 1408; idx += 256)
    prow[idx] = (buf[0][idx] + buf[1][idx]) + (buf[2][idx] + buf[3][idx]);
}

// ---------------- k_out: couple + concat + Wl + residual ----------------
template <int l>
DEV void out_one(int a0, const float* __restrict__ ws,
                 const float* __restrict__ cc0, const float* __restrict__ cc1,
                 const void* __restrict__ fp, void* __restrict__ out, int isb) {
  constexpr int K = cK[l];
  constexpr int NMM = 2 * l + 1;
  constexpr int NS = 4 - l;
  const float* Wl = ws + cWL[l];
  for (int oc = threadIdx.x; oc < NMM * K; oc += 128) {
    int mm = oc / K, cp = oc % K;
    const float* p0 = cc0 + cCB[l] + mm * NS * 32;
    const float* p1 = cc1 + cCB[l] + mm * NS * 32;
    float acc0 = 0.f, acc1 = 0.f;
#pragma unroll 4
    for (int c = 0; c < K; ++c) {
      float w = Wl[c * K + cp];
      acc0 += w * p0[c];
      acc1 += w * p1[c];
    }
    long b0 = ((long)a0 * NMM + mm) * K + cp;
    long b1 = ((long)(a0 + 1) * NMM + mm) * K + cp;
    stf(out, cOUT[l] + b0, ldf(fp, b0, isb) + acc0, isb);
    stf(out, cOUT[l] + b1, ldf(fp, b1, isb) + acc1, isb);
  }
}

__global__ __launch_bounds__(128) void k_out(
    const void* __restrict__ f0, const void* __restrict__ f1,
    const void* __restrict__ f2, const void* __restrict__ f3,
    const int* __restrict__ flag, const float* __restrict__ ws, void* __restrict__ out) {
  __shared__ float cc[2][960];
  int half = threadIdx.x >> 6;
  int t = threadIdx.x & 63;
  int a = blockIdx.x * 2 + half;
  int isb = *flag;
  const float* pool = ws + POOL_OFF + (size_t)a * 1408;
  for (int idx = t; idx < 960; idx += 64) {
    int k = idx & 31, combo = idx >> 5;
    int l = c_tl[combo], mm = c_tmm[combo], s = c_ts[combo];
    int lp = l + s;
    int Ts = c_pl_r[lp] + 1;
    int Ts2 = Ts * Ts;
    const float* U = ws + c_uof_r[lp];
    const float* pr = pool + c_soff_r[lp];
    int m = l * l + mm;
    float sacc = 0.f;
    for (int q = 0; q < Ts2; ++q) sacc += U[q * Ts2 + m] * pr[q * 32 + k];
    cc[half][idx] = sacc;
  }
  __syncthreads();
  int a0 = blockIdx.x * 2;
  out_one<0>(a0, ws, cc[0], cc[1], f0, out, isb);
  out_one<1>(a0, ws, cc[0], cc[1], f1, out, isb);
  out_one<2>(a0, ws, cc[0], cc[1], f2, out, isb);
  out_one<3>(a0, ws, cc[0], cc[1], f3, out, isb);
}

// ---------------- launch ----------------
extern "C" void kernel_launch(void* const* d_in, const int* in_sizes, int n_in,
                              void* d_out, int out_size, void* d_ws, size_t ws_size,
                              hipStream_t stream) {
  (void)n_in; (void)out_size; (void)ws_size;
  bool dictord = (in_sizes[1] == 40000);
  const void* rb[4]; const void* sph[4]; const void* ft[4];
  const void *w1[4], *w2[4], *wl[4];
  for (int l = 0; l < 4; ++l) {
    if (dictord) {
      rb[l]  = d_in[3 * l + 0];
      sph[l] = d_in[3 * l + 1];
      ft[l]  = d_in[3 * l + 2];
      w1[l]  = d_in[17 + 3 * l];
      w2[l]  = d_in[18 + 3 * l];
      wl[l]  = d_in[19 + 3 * l];
    } else {
      rb[l]  = d_in[l];
      sph[l] = d_in[4 + l];
      ft[l]  = d_in[8 + l];
      w1[l]  = d_in[17 + l];
      w2[l]  = d_in[21 + l];
      wl[l]  = d_in[25 + l];
    }
  }
  const int* centers   = (const int*)d_in[12];
  const int* neighbors = (const int*)d_in[13];
  const void* u0 = d_in[14];
  const void* u2 = d_in[15];
  const void* u4 = d_in[16];

  float* ws   = (float*)d_ws;
  int*   flag = (int*)(ws + FLAG_OFF);
  float* rad  = ws + RAD_OFF;
  float* unc  = ws + UNC_OFF;
  float* pool = ws + POOL_OFF;
  int*   cnt   = (int*)(ws + CNT_OFF);
  int*   start = (int*)(ws + START_OFF);
  int*   fill  = (int*)(ws + FILL_OFF);
  int*   elist = (int*)(ws + ELIST_OFF);

  hipMemsetAsync(cnt, 0, N_ATOMS * sizeof(int), stream);
  k_detect<<<1, 64, 0, stream>>>(w2[0], flag);
  k_count<<<(N_EDGES + 255) / 256, 256, 0, stream>>>(centers, cnt);
  k_scan<<<1, 256, 0, stream>>>(cnt, start, fill);
  k_fill<<<(N_EDGES + 255) / 256, 256, 0, stream>>>(centers, fill, elist);
  k_prep<<<208, 256, 0, stream>>>(w1[0], w1[1], w1[2], w1[3],
                                  w2[0], w2[1], w2[2], w2[3],
                                  wl[0], wl[1], wl[2], wl[3],
                                  u0, u2, u4, flag, ws);
  k_radial3<<<1563, 256, 0, stream>>>(rb[0], rb[1], rb[2], rb[3], flag, ws, rad);
  k_uncfeat<<<N_ATOMS / 2, 64, 0, stream>>>(ft[0], ft[1], ft[2], ft[3], flag, ws, unc);
  k_edge3<<<N_ATOMS, 256, 0, stream>>>(sph[0], sph[1], sph[2], sph[3],
                                       start, elist, neighbors, flag, ws, rad, unc, pool);
  k_out<<<N_ATOMS / 2, 128, 0, stream>>>(ft[0], ft[1], ft[2], ft[3], flag, ws, (void*)d_out);
}

// Round 6
// 256.993 us; speedup vs baseline: 1.7517x; 1.3099x over previous
//
#include <hip/hip_runtime.h>
#include <hip/hip_bf16.h>

typedef __hip_bfloat16 bf16;
using short8 = __attribute__((ext_vector_type(8))) short;
using f32x4  = __attribute__((ext_vector_type(4))) float;

#define DEV static __device__ __forceinline__

DEV float b2f(bf16 x) { return __bfloat162float(x); }
// generic load: isb=1 -> buffer is bf16, else f32
DEV float ldf(const void* p, long i, int isb) {
  return isb ? b2f(((const bf16*)p)[i]) : ((const float*)p)[i];
}
DEV void stf(void* p, long i, float v, int isb) {
  if (isb) ((bf16*)p)[i] = __float2bfloat16(v);
  else     ((float*)p)[i] = v;
}
DEV unsigned short f2bu(float f) {
  union { bf16 h; unsigned short u; } v; v.h = __float2bfloat16(f); return v.u;
}
DEV short ldb(const void* p, long i, int isb) {
  if (isb) return ((const short*)p)[i];
  union { bf16 h; short s; } v; v.h = __float2bfloat16(((const float*)p)[i]); return v.s;
}

// ---- problem constants ----
#define N_ATOMS 2500
#define N_EDGES 40000

constexpr int cK[4]    = {128, 96, 64, 32};     // KMAX
constexpr int cPL[4]   = {0, 2, 2, 4};          // padded L per l
constexpr int cLO[4]   = {96, 64, 32, 0};       // channel slice lower bound per l
constexpr int cSOFF[4] = {0, 32, 320, 608};     // section offset in 1408-float atom row
constexpr int cROFF[4] = {0, 128, 224, 288};    // radial row offset (320 floats/edge)
constexpr int cAOF[4]  = {0, 1, 10, 19};        // acc-register offset per l (total 44)
// ws float-offsets (weights converted to f32 by k_prep)
constexpr int cWR1[4] = {0, 512, 896, 1152};
constexpr int cWR2[4] = {1280, 9472, 15616, 19712};
constexpr int cWL[4]  = {21760, 38144, 47360, 51456};
constexpr int cUOF[4] = {52480, 52481, 52481, 52562}; // U[PL[idx]] base
constexpr int FLAG_OFF = 53240;                 // dtype flag (in the 53187..53247 gap)
constexpr int RAD_OFF  = 53248;
constexpr int UNC_OFF  = RAD_OFF + N_EDGES * 320;   // 12,853,248
constexpr int POOL_OFF = UNC_OFF + N_ATOMS * 1408;  // 16,373,248
// CSR area (ints) after pool
constexpr int CSR_OFF   = POOL_OFF + N_ATOMS * 1408; // 19,893,248
constexpr int CNT_OFF   = CSR_OFF;                   // [2500]
constexpr int START_OFF = CSR_OFF + 2500;            // [2501]
constexpr int FILL_OFF  = CSR_OFF + 5008;            // [2500]
constexpr int ELIST_OFF = CSR_OFF + 7512;            // [40000]

constexpr int cCB[4]  = {0, 128, 416, 736};     // concat LDS base per l (x32 floats)
constexpr int cOUT[4] = {0, 320000, 1040000, 1840000};

// k_out combo tables: combo -> (l, mm, s), ordered so LDS addr = combo*32+k
__device__ const int c_tl[30]  = {0,0,0,0, 1,1,1,1,1,1,1,1,1, 2,2,2,2,2,2,2,2,2,2, 3,3,3,3,3,3,3};
__device__ const int c_tmm[30] = {0,0,0,0, 0,0,0,1,1,1,2,2,2, 0,0,1,1,2,2,3,3,4,4, 0,1,2,3,4,5,6};
__device__ const int c_ts[30]  = {0,1,2,3, 0,1,2,0,1,2,0,1,2, 0,1,0,1,0,1,0,1,0,1, 0,0,0,0,0,0,0};
__device__ const int c_soff_r[4] = {0, 32, 320, 608};
__device__ const int c_uof_r[4]  = {52480, 52481, 52481, 52562};
__device__ const int c_pl_r[4]   = {0, 2, 2, 4};

// ---------------- k_detect: decide f32 vs bf16 from Wr2_0's low halves ----------------
__global__ void k_detect(const void* __restrict__ w2_0, int* __restrict__ flag) {
  if (threadIdx.x != 0 || blockIdx.x != 0) return;
  const unsigned* w = (const unsigned*)w2_0;
  int ok = 0;
  for (int i = 0; i < 512; ++i) {
    unsigned lo = w[i] & 0xFFFFu;
    unsigned e = (lo >> 7) & 0xFFu;
    if (lo == 0u || (e >= 100u && e <= 140u)) ok++;
  }
  *flag = (ok >= 256) ? 1 : 0;
}

// ---------------- k_prep: weights/U (either dtype) -> f32 in ws ----------------
__global__ __launch_bounds__(256) void k_prep(
    const void* __restrict__ w10, const void* __restrict__ w11, const void* __restrict__ w12, const void* __restrict__ w13,
    const void* __restrict__ w20, const void* __restrict__ w21, const void* __restrict__ w22, const void* __restrict__ w23,
    const void* __restrict__ wl0, const void* __restrict__ wl1, const void* __restrict__ wl2, const void* __restrict__ wl3,
    const void* __restrict__ u0, const void* __restrict__ u2, const void* __restrict__ u4,
    const int* __restrict__ flag, float* __restrict__ ws) {
  int i = blockIdx.x * 256 + threadIdx.x;
  if (i >= 53187) return;
  int isb = *flag;
  const void* src; int base;
  if      (i < 512)   { src = w10; base = 0; }
  else if (i < 896)   { src = w11; base = 512; }
  else if (i < 1152)  { src = w12; base = 896; }
  else if (i < 1280)  { src = w13; base = 1152; }
  else if (i < 9472)  { src = w20; base = 1280; }
  else if (i < 15616) { src = w21; base = 9472; }
  else if (i < 19712) { src = w22; base = 15616; }
  else if (i < 21760) { src = w23; base = 19712; }
  else if (i < 38144) { src = wl0; base = 21760; }
  else if (i < 47360) { src = wl1; base = 38144; }
  else if (i < 51456) { src = wl2; base = 47360; }
  else if (i < 52480) { src = wl3; base = 51456; }
  else if (i < 52481) { src = u0;  base = 52480; }
  else if (i < 52562) { src = u2;  base = 52481; }
  else                { src = u4;  base = 52562; }
  ws[i] = ldf(src, i - base, isb);
}

// ---------------- CSR build: count / scan / fill ----------------
__global__ __launch_bounds__(256) void k_count(const int* __restrict__ centers, int* __restrict__ cnt) {
  int e = blockIdx.x * 256 + threadIdx.x;
  if (e < N_EDGES) atomicAdd(&cnt[centers[e]], 1);
}

__global__ __launch_bounds__(256) void k_scan(const int* __restrict__ cnt,
                                              int* __restrict__ start, int* __restrict__ fill) {
  __shared__ int part[256];
  int t = threadIdx.x;
  int loc[10];
  int s = 0;
  int base = t * 10;
#pragma unroll
  for (int i = 0; i < 10; ++i) {
    int c = (base + i < N_ATOMS) ? cnt[base + i] : 0;
    loc[i] = s; s += c;
  }
  part[t] = s;
  __syncthreads();
  for (int off = 1; off < 256; off <<= 1) {
    int v = part[t];
    if (t >= off) v += part[t - off];
    __syncthreads();
    part[t] = v;
    __syncthreads();
  }
  int excl = (t == 0) ? 0 : part[t - 1];
#pragma unroll
  for (int i = 0; i < 10; ++i) {
    if (base + i < N_ATOMS) {
      start[base + i] = excl + loc[i];
      fill[base + i]  = excl + loc[i];
    }
  }
  if (t == 255) start[N_ATOMS] = part[255];
}

__global__ __launch_bounds__(256) void k_fill(const int* __restrict__ centers,
                                              int* __restrict__ fill, int* __restrict__ elist) {
  int e = blockIdx.x * 256 + threadIdx.x;
  if (e >= N_EDGES) return;
  int pos = atomicAdd(&fill[centers[e]], 1);
  elist[pos] = e;
}

// ---------------- k_radial4: MFMA GEMM  silu(rb@Wr1) @ Wr2 ----------------
// Block = 64 edges of one l, 4 waves. Phase1: H[64][64] bf16 in LDS (VALU).
// Phase2: 16x16x32 bf16 MFMA, A = H (LDS), B = Wr2 (global), C = rad (f32).
template <int l>
DEV void radial_body(const void* __restrict__ rb, const void* __restrict__ w2,
                     int isb, const float* __restrict__ ws, float* __restrict__ rad,
                     int e0, int tid, unsigned short (*H)[72]) {
  constexpr int NM = (l == 0) ? 8 : (l == 1) ? 6 : (l == 2) ? 4 : 2;
  constexpr int K  = cK[l];
  const float* Wr1f = ws + cWR1[l];
  // ---- phase 1: H = silu(rb @ Wr1), one (edge, 16-j slice) per thread ----
  {
    int e  = e0 + (tid & 63);
    int j0 = (tid >> 6) * 16;
    float rbv[NM];
#pragma unroll
    for (int n = 0; n < NM; ++n) rbv[n] = ldf(rb, (long)e * NM + n, isb);
    float h[16];
#pragma unroll
    for (int j = 0; j < 16; ++j) h[j] = 0.f;
#pragma unroll
    for (int n = 0; n < NM; ++n) {
      float rv = rbv[n];
      const float4* wp = reinterpret_cast<const float4*>(Wr1f + n * 64 + j0);
#pragma unroll
      for (int q = 0; q < 4; ++q) {
        float4 w = wp[q];
        h[4 * q + 0] += rv * w.x;
        h[4 * q + 1] += rv * w.y;
        h[4 * q + 2] += rv * w.z;
        h[4 * q + 3] += rv * w.w;
      }
    }
    unsigned short* hrow = H[tid & 63];
#pragma unroll
    for (int j = 0; j < 16; j += 2) {
      float a0 = h[j], a1 = h[j + 1];
      a0 = a0 * (1.0f / (1.0f + __expf(-a0)));
      a1 = a1 * (1.0f / (1.0f + __expf(-a1)));
      unsigned w = (unsigned)f2bu(a0) | ((unsigned)f2bu(a1) << 16);
      *reinterpret_cast<unsigned*>(&hrow[j0 + j]) = w;
    }
  }
  __syncthreads();
  // ---- phase 2: rad[.., cROFF+c] = H @ Wr2 ----
  int wv = tid >> 6, lane = tid & 63;
  constexpr int NET = (l <= 1) ? 4 : (l == 2 ? 2 : 1);
  int c0, et0;
  bool active = true;
  if constexpr (l == 0)      { c0 = wv * 32;       et0 = 0; }
  else if constexpr (l == 1) { c0 = wv * 32;       et0 = 0; active = (wv < 3); }
  else if constexpr (l == 2) { c0 = (wv & 1) * 32; et0 = (wv >> 1) * 2; }
  else                       { c0 = 0;             et0 = wv; }
  if (!active) return;
  int ln15 = lane & 15, lhi = lane >> 4;
  // B fragments: Bf[col-tile][k-step]; elem i of lane -> B[k = ks*32+lhi*8+i][col]
  short8 Bf[2][2];
#pragma unroll
  for (int ct = 0; ct < 2; ++ct)
#pragma unroll
    for (int ks = 0; ks < 2; ++ks) {
      int col = c0 + ct * 16 + ln15;
      int kb  = ks * 32 + lhi * 8;
#pragma unroll
      for (int i = 0; i < 8; ++i)
        Bf[ct][ks][i] = ldb(w2, (long)(kb + i) * K + col, isb);
    }
  f32x4 acc[NET][2];
#pragma unroll
  for (int et = 0; et < NET; ++et)
#pragma unroll
    for (int ct = 0; ct < 2; ++ct) acc[et][ct] = (f32x4){0.f, 0.f, 0.f, 0.f};
#pragma unroll
  for (int et = 0; et < NET; ++et) {
#pragma unroll
    for (int ks = 0; ks < 2; ++ks) {
      short8 Af = *reinterpret_cast<const short8*>(&H[(et0 + et) * 16 + ln15][ks * 32 + lhi * 8]);
      acc[et][0] = __builtin_amdgcn_mfma_f32_16x16x32_bf16(Af, Bf[0][ks], acc[et][0], 0, 0, 0);
      acc[et][1] = __builtin_amdgcn_mfma_f32_16x16x32_bf16(Af, Bf[1][ks], acc[et][1], 0, 0, 0);
    }
  }
  // C/D layout (HW-verified): col = lane&15, row = (lane>>4)*4 + r
#pragma unroll
  for (int et = 0; et < NET; ++et)
#pragma unroll
    for (int ct = 0; ct < 2; ++ct)
#pragma unroll
      for (int r = 0; r < 4; ++r) {
        int erow = (et0 + et) * 16 + lhi * 4 + r;
        int col  = c0 + ct * 16 + ln15;
        rad[(size_t)(e0 + erow) * 320 + cROFF[l] + col] = acc[et][ct][r];
      }
}

__global__ __launch_bounds__(256) void k_radial4(
    const void* __restrict__ rb0, const void* __restrict__ rb1,
    const void* __restrict__ rb2, const void* __restrict__ rb3,
    const void* __restrict__ w20, const void* __restrict__ w21,
    const void* __restrict__ w22, const void* __restrict__ w23,
    const int* __restrict__ flag, const float* __restrict__ ws, float* __restrict__ rad) {
  __shared__ __align__(16) unsigned short H[64][72];
  int isb = *flag;
  int l  = blockIdx.x / 625;
  int e0 = (blockIdx.x - l * 625) * 64;
  int tid = threadIdx.x;
  switch (l) {
    case 0: radial_body<0>(rb0, w20, isb, ws, rad, e0, tid, H); break;
    case 1: radial_body<1>(rb1, w21, isb, ws, rad, e0, tid, H); break;
    case 2: radial_body<2>(rb2, w22, isb, ws, rad, e0, tid, H); break;
    default: radial_body<3>(rb3, w23, isb, ws, rad, e0, tid, H); break;
  }
}

// ---------------- k_uncfeat: per-atom uncoupled features ----------------
template <int l>
DEV void unc_one(int a, int k,
                 const void* __restrict__ f0, const void* __restrict__ f1,
                 const void* __restrict__ f2, const void* __restrict__ f3,
                 const float* __restrict__ ws, float* __restrict__ dst, int isb) {
  constexpr int T = cPL[l] + 1;
  constexpr int T2 = T * T;
  constexpr int M = (l + 1) * (l + 1);
  const float* U = ws + cUOF[l];
  const void* fps[4] = {f0, f1, f2, f3};
  float fc[M];
#pragma unroll
  for (int lp = 0; lp <= l; ++lp) {
    const void* fp = fps[lp];
#pragma unroll
    for (int mm = 0; mm < 2 * lp + 1; ++mm)
      fc[lp * lp + mm] = ldf(fp, ((long)a * (2 * lp + 1) + mm) * cK[lp] + cLO[l] + k, isb);
  }
#pragma unroll
  for (int q = 0; q < T2; ++q) {
    float s = 0.f;
#pragma unroll
    for (int m = 0; m < M; ++m) s += U[q * T2 + m] * fc[m];
    dst[cSOFF[l] + q * 32 + k] = s;
  }
}

__global__ __launch_bounds__(64) void k_uncfeat(
    const void* __restrict__ f0, const void* __restrict__ f1,
    const void* __restrict__ f2, const void* __restrict__ f3,
    const int* __restrict__ flag, const float* __restrict__ ws, float* __restrict__ unc) {
  int a = blockIdx.x * 2 + (threadIdx.x >> 5);
  int k = threadIdx.x & 31;
  if (a >= N_ATOMS) return;
  int isb = *flag;
  float* dst = unc + (size_t)a * 1408;
  unc_one<0>(a, k, f0, f1, f2, f3, ws, dst, isb);
  unc_one<1>(a, k, f0, f1, f2, f3, ws, dst, isb);
  unc_one<2>(a, k, f0, f1, f2, f3, ws, dst, isb);
  unc_one<3>(a, k, f0, f1, f2, f3, ws, dst, isb);
}

// ---------------- k_edge3: CSR accumulation with S-factorized uncouple ----------------
template <int l>
DEV void edge_acc3(int e, int k, const float* __restrict__ rrow,
                   const void* __restrict__ s0, const void* __restrict__ s1,
                   const void* __restrict__ s2, const void* __restrict__ s3,
                   const float* __restrict__ ws, const float* __restrict__ frow,
                   float* __restrict__ accl, int isb) {
  constexpr int T = cPL[l] + 1;
  constexpr int T2 = T * T;
  const float* U = ws + cUOF[l];
  const void* sps[4] = {s0, s1, s2, s3};
  float rvl[l + 1];
#pragma unroll
  for (int lp = 0; lp <= l; ++lp) rvl[lp] = rrow[cROFF[lp] + cLO[l] + k];

  if constexpr (l == 0) {
    float S = U[0] * ldf(s0, e, isb);
    accl[0] += rvl[0] * S * frow[cSOFF[0] + k];
    return;
  }

  int qc = (k < T2) ? k : 0;
  float S[l + 1];
#pragma unroll
  for (int lp = 0; lp <= l; ++lp) {
    float s = 0.f;
    const void* sp = sps[lp];
#pragma unroll
    for (int mm = 0; mm < 2 * lp + 1; ++mm)
      s += U[qc * T2 + lp * lp + mm] * ldf(sp, (long)e * (2 * lp + 1) + mm, isb);
    S[lp] = s;
  }
  float V[T2];
#pragma unroll
  for (int q = 0; q < T2; ++q) {
    float v = 0.f;
#pragma unroll
    for (int lp = 0; lp <= l; ++lp) v += rvl[lp] * __shfl(S[lp], q, 32);
    V[q] = v;
  }
  float F[T2];
#pragma unroll
  for (int q = 0; q < T2; ++q) F[q] = frow[cSOFF[l] + q * 32 + k];
#pragma unroll
  for (int i = 0; i < T; ++i) {
#pragma unroll
    for (int j = 0; j < T; ++j) {
      float c = 0.f;
#pragma unroll
      for (int t = 0; t < T; ++t) c += V[i * T + t] * F[t * T + j];
      accl[i * T + j] += c;
    }
  }
}

__global__ __launch_bounds__(256) void k_edge3(
    const void* __restrict__ s0, const void* __restrict__ s1,
    const void* __restrict__ s2, const void* __restrict__ s3,
    const int* __restrict__ start, const int* __restrict__ elist,
    const int* __restrict__ neighbors, const int* __restrict__ flag,
    const float* __restrict__ ws, const float* __restrict__ rad,
    const float* __restrict__ unc, float* __restrict__ pool) {
  int a = blockIdx.x;
  int tid = threadIdx.x;
  int wv = tid >> 6;           // wave 0..3
  int k = tid & 31;            // channel
  int strm = tid >> 5;         // 8 edge streams
  int isb = *flag;
  int beg = start[a], end = start[a + 1];

  float acc[44];
#pragma unroll
  for (int j = 0; j < 44; ++j) acc[j] = 0.f;

  for (int i = beg + strm; i < end; i += 8) {
    int e = elist[i];
    int ne = neighbors[e];
    const float* rrow = rad + (size_t)e * 320;
    const float* frow = unc + (size_t)ne * 1408;
    edge_acc3<0>(e, k, rrow, s0, s1, s2, s3, ws, frow, acc + cAOF[0], isb);
    edge_acc3<1>(e, k, rrow, s0, s1, s2, s3, ws, frow, acc + cAOF[1], isb);
    edge_acc3<2>(e, k, rrow, s0, s1, s2, s3, ws, frow, acc + cAOF[2], isb);
    edge_acc3<3>(e, k, rrow, s0, s1, s2, s3, ws, frow, acc + cAOF[3], isb);
  }
#pragma unroll
  for (int j = 0; j < 44; ++j) acc[j] += __shfl_xor(acc[j], 32);

  __shared__ float buf[4][1408];
  if ((tid & 32) == 0) {
#pragma unroll
    for (int l = 0; l < 4; ++l) {
      int T2 = (cPL[l] + 1) * (cPL[l] + 1);
      for (int q = 0; q < T2; ++q)
        buf[wv][cSOFF[l] + q * 32 + k] = acc[cAOF[l] + q];
    }
  }
  __syncthreads();
  float* prow = pool + (size_t)a * 1408;
  for (int idx = tid; idx < 1408; idx += 256)
    prow[idx] = (buf[0][idx] + buf[1][idx]) + (buf[2][idx] + buf[3][idx]);
}

// ---------------- k_out: couple + concat + Wl + residual ----------------
template <int l>
DEV void out_one(int a0, const float* __restrict__ ws,
                 const float* __restrict__ cc0, const float* __restrict__ cc1,
                 const void* __restrict__ fp, void* __restrict__ out, int isb) {
  constexpr int K = cK[l];
  constexpr int NMM = 2 * l + 1;
  constexpr int NS = 4 - l;
  const float* Wl = ws + cWL[l];
  for (int oc = threadIdx.x; oc < NMM * K; oc += 128) {
    int mm = oc / K, cp = oc % K;
    const float* p0 = cc0 + cCB[l] + mm * NS * 32;
    const float* p1 = cc1 + cCB[l] + mm * NS * 32;
    float acc0 = 0.f, acc1 = 0.f;
#pragma unroll 4
    for (int c = 0; c < K; ++c) {
      float w = Wl[c * K + cp];
      acc0 += w * p0[c];
      acc1 += w * p1[c];
    }
    long b0 = ((long)a0 * NMM + mm) * K + cp;
    long b1 = ((long)(a0 + 1) * NMM + mm) * K + cp;
    stf(out, cOUT[l] + b0, ldf(fp, b0, isb) + acc0, isb);
    stf(out, cOUT[l] + b1, ldf(fp, b1, isb) + acc1, isb);
  }
}

__global__ __launch_bounds__(128) void k_out(
    const void* __restrict__ f0, const void* __restrict__ f1,
    const void* __restrict__ f2, const void* __restrict__ f3,
    const int* __restrict__ flag, const float* __restrict__ ws, void* __restrict__ out) {
  __shared__ float cc[2][960];
  int half = threadIdx.x >> 6;
  int t = threadIdx.x & 63;
  int a = blockIdx.x * 2 + half;
  int isb = *flag;
  const float* pool = ws + POOL_OFF + (size_t)a * 1408;
  for (int idx = t; idx < 960; idx += 64) {
    int k = idx & 31, combo = idx >> 5;
    int l = c_tl[combo], mm = c_tmm[combo], s = c_ts[combo];
    int lp = l + s;
    int Ts = c_pl_r[lp] + 1;
    int Ts2 = Ts * Ts;
    const float* U = ws + c_uof_r[lp];
    const float* pr = pool + c_soff_r[lp];
    int m = l * l + mm;
    float sacc = 0.f;
    for (int q = 0; q < Ts2; ++q) sacc += U[q * Ts2 + m] * pr[q * 32 + k];
    cc[half][idx] = sacc;
  }
  __syncthreads();
  int a0 = blockIdx.x * 2;
  out_one<0>(a0, ws, cc[0], cc[1], f0, out, isb);
  out_one<1>(a0, ws, cc[0], cc[1], f1, out, isb);
  out_one<2>(a0, ws, cc[0], cc[1], f2, out, isb);
  out_one<3>(a0, ws, cc[0], cc[1], f3, out, isb);
}

// ---------------- launch ----------------
extern "C" void kernel_launch(void* const* d_in, const int* in_sizes, int n_in,
                              void* d_out, int out_size, void* d_ws, size_t ws_size,
                              hipStream_t stream) {
  (void)n_in; (void)out_size; (void)ws_size;
  bool dictord = (in_sizes[1] == 40000);
  const void* rb[4]; const void* sph[4]; const void* ft[4];
  const void *w1[4], *w2[4], *wl[4];
  for (int l = 0; l < 4; ++l) {
    if (dictord) {
      rb[l]  = d_in[3 * l + 0];
      sph[l] = d_in[3 * l + 1];
      ft[l]  = d_in[3 * l + 2];
      w1[l]  = d_in[17 + 3 * l];
      w2[l]  = d_in[18 + 3 * l];
      wl[l]  = d_in[19 + 3 * l];
    } else {
      rb[l]  = d_in[l];
      sph[l] = d_in[4 + l];
      ft[l]  = d_in[8 + l];
      w1[l]  = d_in[17 + l];
      w2[l]  = d_in[21 + l];
      wl[l]  = d_in[25 + l];
    }
  }
  const int* centers   = (const int*)d_in[12];
  const int* neighbors = (const int*)d_in[13];
  const void* u0 = d_in[14];
  const void* u2 = d_in[15];
  const void* u4 = d_in[16];

  float* ws   = (float*)d_ws;
  int*   flag = (int*)(ws + FLAG_OFF);
  float* rad  = ws + RAD_OFF;
  float* unc  = ws + UNC_OFF;
  float* pool = ws + POOL_OFF;
  int*   cnt   = (int*)(ws + CNT_OFF);
  int*   start = (int*)(ws + START_OFF);
  int*   fill  = (int*)(ws + FILL_OFF);
  int*   elist = (int*)(ws + ELIST_OFF);

  hipMemsetAsync(cnt, 0, N_ATOMS * sizeof(int), stream);
  k_detect<<<1, 64, 0, stream>>>(w2[0], flag);
  k_count<<<(N_EDGES + 255) / 256, 256, 0, stream>>>(centers, cnt);
  k_scan<<<1, 256, 0, stream>>>(cnt, start, fill);
  k_fill<<<(N_EDGES + 255) / 256, 256, 0, stream>>>(centers, fill, elist);
  k_prep<<<208, 256, 0, stream>>>(w1[0], w1[1], w1[2], w1[3],
                                  w2[0], w2[1], w2[2], w2[3],
                                  wl[0], wl[1], wl[2], wl[3],
                                  u0, u2, u4, flag, ws);
  k_radial4<<<2500, 256, 0, stream>>>(rb[0], rb[1], rb[2], rb[3],
                                      w2[0], w2[1], w2[2], w2[3], flag, ws, rad);
  k_uncfeat<<<N_ATOMS / 2, 64, 0, stream>>>(ft[0], ft[1], ft[2], ft[3], flag, ws, unc);
  k_edge3<<<N_ATOMS, 256, 0, stream>>>(sph[0], sph[1], sph[2], sph[3],
                                       start, elist, neighbors, flag, ws, rad, unc, pool);
  k_out<<<N_ATOMS / 2, 128, 0, stream>>>(ft[0], ft[1], ft[2], ft[3], flag, ws, (void*)d_out);
}

// Round 7
// 214.447 us; speedup vs baseline: 2.0993x; 1.1984x over previous
//
#include <hip/hip_runtime.h>
#include <hip/hip_bf16.h>

typedef __hip_bfloat16 bf16;
using short8 = __attribute__((ext_vector_type(8))) short;
using f32x4  = __attribute__((ext_vector_type(4))) float;

#define DEV static __device__ __forceinline__

DEV float b2f(bf16 x) { return __bfloat162float(x); }
DEV float ldf(const void* p, long i, int isb) {
  return isb ? b2f(((const bf16*)p)[i]) : ((const float*)p)[i];
}
DEV void stf(void* p, long i, float v, int isb) {
  if (isb) ((bf16*)p)[i] = __float2bfloat16(v);
  else     ((float*)p)[i] = v;
}
DEV unsigned short f2bu(float f) {
  union { bf16 h; unsigned short u; } v; v.h = __float2bfloat16(f); return v.u;
}
DEV float bu2f(unsigned short u) {
  unsigned w = ((unsigned)u) << 16;
  union { unsigned u; float f; } v; v.u = w; return v.f;
}
DEV short ldb(const void* p, long i, int isb) {
  if (isb) return ((const short*)p)[i];
  union { bf16 h; short s; } v; v.h = __float2bfloat16(((const float*)p)[i]); return v.s;
}

// ---- problem constants ----
#define N_ATOMS 2500
#define N_EDGES 40000

constexpr int cK[4]    = {128, 96, 64, 32};     // KMAX
constexpr int cPL[4]   = {0, 2, 2, 4};          // padded L per l
constexpr int cLO[4]   = {96, 64, 32, 0};       // channel slice lower bound per l
constexpr int cSOFF[4] = {0, 32, 320, 608};     // section offset in 1408-float atom row
constexpr int cROFF[4] = {0, 128, 224, 288};    // radial row offset (320 floats/edge)
constexpr int cAOF[4]  = {0, 1, 10, 19};        // acc-register offset per l (total 44)
// ws float-offsets (weights converted to f32 by k_prep)
constexpr int cWR1[4] = {0, 512, 896, 1152};
constexpr int cWR2[4] = {1280, 9472, 15616, 19712};
constexpr int cWL[4]  = {21760, 38144, 47360, 51456};
constexpr int cUOF[4] = {52480, 52481, 52481, 52562}; // U[PL[idx]] base
constexpr int FLAG_OFF = 53240;
constexpr int RAD_OFF  = 53248;
constexpr int UNC_OFF  = RAD_OFF + N_EDGES * 320;   // 12,853,248 (now ushort区: 2500*1408 bf16)
constexpr int CCG_OFF  = UNC_OFF + N_ATOMS * 704;   // float-offset; ccg = 2500*960 bf16 (1.2M floats)
constexpr int CSR_OFF   = CCG_OFF + N_ATOMS * 480;  // ints
constexpr int CNT_OFF   = CSR_OFF;                   // [2500]
constexpr int START_OFF = CSR_OFF + 2500;            // [2501]
constexpr int FILL_OFF  = CSR_OFF + 5008;            // [2500]
constexpr int ELIST_OFF = CSR_OFF + 7512;            // [40000]

constexpr int cCB[4]  = {0, 128, 416, 736};     // concat base per atom row (960)
constexpr int cOUT[4] = {0, 320000, 1040000, 1840000};

// combo tables: combo -> (l, mm, s); concat idx = combo*32 + k
__device__ const int c_tl[30]  = {0,0,0,0, 1,1,1,1,1,1,1,1,1, 2,2,2,2,2,2,2,2,2,2, 3,3,3,3,3,3,3};
__device__ const int c_tmm[30] = {0,0,0,0, 0,0,0,1,1,1,2,2,2, 0,0,1,1,2,2,3,3,4,4, 0,1,2,3,4,5,6};
__device__ const int c_ts[30]  = {0,1,2,3, 0,1,2,0,1,2,0,1,2, 0,1,0,1,0,1,0,1,0,1, 0,0,0,0,0,0,0};
__device__ const int c_soff_r[4] = {0, 32, 320, 608};
__device__ const int c_uof_r[4]  = {52480, 52481, 52481, 52562};
__device__ const int c_pl_r[4]   = {0, 2, 2, 4};

// ---------------- k_detect ----------------
__global__ void k_detect(const void* __restrict__ w2_0, int* __restrict__ flag) {
  if (threadIdx.x != 0 || blockIdx.x != 0) return;
  const unsigned* w = (const unsigned*)w2_0;
  int ok = 0;
  for (int i = 0; i < 512; ++i) {
    unsigned lo = w[i] & 0xFFFFu;
    unsigned e = (lo >> 7) & 0xFFu;
    if (lo == 0u || (e >= 100u && e <= 140u)) ok++;
  }
  *flag = (ok >= 256) ? 1 : 0;
}

// ---------------- k_prep ----------------
__global__ __launch_bounds__(256) void k_prep(
    const void* __restrict__ w10, const void* __restrict__ w11, const void* __restrict__ w12, const void* __restrict__ w13,
    const void* __restrict__ w20, const void* __restrict__ w21, const void* __restrict__ w22, const void* __restrict__ w23,
    const void* __restrict__ wl0, const void* __restrict__ wl1, const void* __restrict__ wl2, const void* __restrict__ wl3,
    const void* __restrict__ u0, const void* __restrict__ u2, const void* __restrict__ u4,
    const int* __restrict__ flag, float* __restrict__ ws) {
  int i = blockIdx.x * 256 + threadIdx.x;
  if (i >= 53187) return;
  int isb = *flag;
  const void* src; int base;
  if      (i < 512)   { src = w10; base = 0; }
  else if (i < 896)   { src = w11; base = 512; }
  else if (i < 1152)  { src = w12; base = 896; }
  else if (i < 1280)  { src = w13; base = 1152; }
  else if (i < 9472)  { src = w20; base = 1280; }
  else if (i < 15616) { src = w21; base = 9472; }
  else if (i < 19712) { src = w22; base = 15616; }
  else if (i < 21760) { src = w23; base = 19712; }
  else if (i < 38144) { src = wl0; base = 21760; }
  else if (i < 47360) { src = wl1; base = 38144; }
  else if (i < 51456) { src = wl2; base = 47360; }
  else if (i < 52480) { src = wl3; base = 51456; }
  else if (i < 52481) { src = u0;  base = 52480; }
  else if (i < 52562) { src = u2;  base = 52481; }
  else                { src = u4;  base = 52562; }
  ws[i] = ldf(src, i - base, isb);
}

// ---------------- CSR build ----------------
__global__ __launch_bounds__(256) void k_count(const int* __restrict__ centers, int* __restrict__ cnt) {
  int e = blockIdx.x * 256 + threadIdx.x;
  if (e < N_EDGES) atomicAdd(&cnt[centers[e]], 1);
}

__global__ __launch_bounds__(256) void k_scan(const int* __restrict__ cnt,
                                              int* __restrict__ start, int* __restrict__ fill) {
  __shared__ int part[256];
  int t = threadIdx.x;
  int loc[10];
  int s = 0;
  int base = t * 10;
#pragma unroll
  for (int i = 0; i < 10; ++i) {
    int c = (base + i < N_ATOMS) ? cnt[base + i] : 0;
    loc[i] = s; s += c;
  }
  part[t] = s;
  __syncthreads();
  for (int off = 1; off < 256; off <<= 1) {
    int v = part[t];
    if (t >= off) v += part[t - off];
    __syncthreads();
    part[t] = v;
    __syncthreads();
  }
  int excl = (t == 0) ? 0 : part[t - 1];
#pragma unroll
  for (int i = 0; i < 10; ++i) {
    if (base + i < N_ATOMS) {
      start[base + i] = excl + loc[i];
      fill[base + i]  = excl + loc[i];
    }
  }
  if (t == 255) start[N_ATOMS] = part[255];
}

__global__ __launch_bounds__(256) void k_fill(const int* __restrict__ centers,
                                              int* __restrict__ fill, int* __restrict__ elist) {
  int e = blockIdx.x * 256 + threadIdx.x;
  if (e >= N_EDGES) return;
  int pos = atomicAdd(&fill[centers[e]], 1);
  elist[pos] = e;
}

// ---------------- k_radial4: MFMA GEMM  silu(rb@Wr1) @ Wr2 ----------------
template <int l>
DEV void radial_body(const void* __restrict__ rb, const void* __restrict__ w2,
                     int isb, const float* __restrict__ ws, float* __restrict__ rad,
                     int e0, int tid, unsigned short (*H)[72]) {
  constexpr int NM = (l == 0) ? 8 : (l == 1) ? 6 : (l == 2) ? 4 : 2;
  constexpr int K  = cK[l];
  const float* Wr1f = ws + cWR1[l];
  {
    int e  = e0 + (tid & 63);
    int j0 = (tid >> 6) * 16;
    float rbv[NM];
#pragma unroll
    for (int n = 0; n < NM; ++n) rbv[n] = ldf(rb, (long)e * NM + n, isb);
    float h[16];
#pragma unroll
    for (int j = 0; j < 16; ++j) h[j] = 0.f;
#pragma unroll
    for (int n = 0; n < NM; ++n) {
      float rv = rbv[n];
      const float4* wp = reinterpret_cast<const float4*>(Wr1f + n * 64 + j0);
#pragma unroll
      for (int q = 0; q < 4; ++q) {
        float4 w = wp[q];
        h[4 * q + 0] += rv * w.x;
        h[4 * q + 1] += rv * w.y;
        h[4 * q + 2] += rv * w.z;
        h[4 * q + 3] += rv * w.w;
      }
    }
    unsigned short* hrow = H[tid & 63];
#pragma unroll
    for (int j = 0; j < 16; j += 2) {
      float a0 = h[j], a1 = h[j + 1];
      a0 = a0 * (1.0f / (1.0f + __expf(-a0)));
      a1 = a1 * (1.0f / (1.0f + __expf(-a1)));
      unsigned w = (unsigned)f2bu(a0) | ((unsigned)f2bu(a1) << 16);
      *reinterpret_cast<unsigned*>(&hrow[j0 + j]) = w;
    }
  }
  __syncthreads();
  int wv = tid >> 6, lane = tid & 63;
  constexpr int NET = (l <= 1) ? 4 : (l == 2 ? 2 : 1);
  int c0, et0;
  bool active = true;
  if constexpr (l == 0)      { c0 = wv * 32;       et0 = 0; }
  else if constexpr (l == 1) { c0 = wv * 32;       et0 = 0; active = (wv < 3); }
  else if constexpr (l == 2) { c0 = (wv & 1) * 32; et0 = (wv >> 1) * 2; }
  else                       { c0 = 0;             et0 = wv; }
  if (!active) return;
  int ln15 = lane & 15, lhi = lane >> 4;
  short8 Bf[2][2];
#pragma unroll
  for (int ct = 0; ct < 2; ++ct)
#pragma unroll
    for (int ks = 0; ks < 2; ++ks) {
      int col = c0 + ct * 16 + ln15;
      int kb  = ks * 32 + lhi * 8;
#pragma unroll
      for (int i = 0; i < 8; ++i)
        Bf[ct][ks][i] = ldb(w2, (long)(kb + i) * K + col, isb);
    }
  f32x4 acc[NET][2];
#pragma unroll
  for (int et = 0; et < NET; ++et)
#pragma unroll
    for (int ct = 0; ct < 2; ++ct) acc[et][ct] = (f32x4){0.f, 0.f, 0.f, 0.f};
#pragma unroll
  for (int et = 0; et < NET; ++et) {
#pragma unroll
    for (int ks = 0; ks < 2; ++ks) {
      short8 Af = *reinterpret_cast<const short8*>(&H[(et0 + et) * 16 + ln15][ks * 32 + lhi * 8]);
      acc[et][0] = __builtin_amdgcn_mfma_f32_16x16x32_bf16(Af, Bf[0][ks], acc[et][0], 0, 0, 0);
      acc[et][1] = __builtin_amdgcn_mfma_f32_16x16x32_bf16(Af, Bf[1][ks], acc[et][1], 0, 0, 0);
    }
  }
#pragma unroll
  for (int et = 0; et < NET; ++et)
#pragma unroll
    for (int ct = 0; ct < 2; ++ct)
#pragma unroll
      for (int r = 0; r < 4; ++r) {
        int erow = (et0 + et) * 16 + lhi * 4 + r;
        int col  = c0 + ct * 16 + ln15;
        rad[(size_t)(e0 + erow) * 320 + cROFF[l] + col] = acc[et][ct][r];
      }
}

__global__ __launch_bounds__(256) void k_radial4(
    const void* __restrict__ rb0, const void* __restrict__ rb1,
    const void* __restrict__ rb2, const void* __restrict__ rb3,
    const void* __restrict__ w20, const void* __restrict__ w21,
    const void* __restrict__ w22, const void* __restrict__ w23,
    const int* __restrict__ flag, const float* __restrict__ ws, float* __restrict__ rad) {
  __shared__ __align__(16) unsigned short H[64][72];
  int isb = *flag;
  int l  = blockIdx.x / 625;
  int e0 = (blockIdx.x - l * 625) * 64;
  int tid = threadIdx.x;
  switch (l) {
    case 0: radial_body<0>(rb0, w20, isb, ws, rad, e0, tid, H); break;
    case 1: radial_body<1>(rb1, w21, isb, ws, rad, e0, tid, H); break;
    case 2: radial_body<2>(rb2, w22, isb, ws, rad, e0, tid, H); break;
    default: radial_body<3>(rb3, w23, isb, ws, rad, e0, tid, H); break;
  }
}

// ---------------- k_uncfeat: per-atom uncoupled features (bf16 out) ----------------
template <int l>
DEV void unc_one(int a, int k,
                 const void* __restrict__ f0, const void* __restrict__ f1,
                 const void* __restrict__ f2, const void* __restrict__ f3,
                 const float* __restrict__ ws, unsigned short* __restrict__ dst, int isb) {
  constexpr int T = cPL[l] + 1;
  constexpr int T2 = T * T;
  constexpr int M = (l + 1) * (l + 1);
  const float* U = ws + cUOF[l];
  const void* fps[4] = {f0, f1, f2, f3};
  float fc[M];
#pragma unroll
  for (int lp = 0; lp <= l; ++lp) {
    const void* fp = fps[lp];
#pragma unroll
    for (int mm = 0; mm < 2 * lp + 1; ++mm)
      fc[lp * lp + mm] = ldf(fp, ((long)a * (2 * lp + 1) + mm) * cK[lp] + cLO[l] + k, isb);
  }
#pragma unroll
  for (int q = 0; q < T2; ++q) {
    float s = 0.f;
#pragma unroll
    for (int m = 0; m < M; ++m) s += U[q * T2 + m] * fc[m];
    dst[cSOFF[l] + q * 32 + k] = f2bu(s);
  }
}

__global__ __launch_bounds__(64) void k_uncfeat(
    const void* __restrict__ f0, const void* __restrict__ f1,
    const void* __restrict__ f2, const void* __restrict__ f3,
    const int* __restrict__ flag, const float* __restrict__ ws, unsigned short* __restrict__ unc) {
  int a = blockIdx.x * 2 + (threadIdx.x >> 5);
  int k = threadIdx.x & 31;
  if (a >= N_ATOMS) return;
  int isb = *flag;
  unsigned short* dst = unc + (size_t)a * 1408;
  unc_one<0>(a, k, f0, f1, f2, f3, ws, dst, isb);
  unc_one<1>(a, k, f0, f1, f2, f3, ws, dst, isb);
  unc_one<2>(a, k, f0, f1, f2, f3, ws, dst, isb);
  unc_one<3>(a, k, f0, f1, f2, f3, ws, dst, isb);
}

// ---------------- k_edge3: CSR accumulation + fused couple/concat epilogue ----------------
template <int l>
DEV void edge_acc3(int e, int k, const float* __restrict__ rrow,
                   const void* __restrict__ s0, const void* __restrict__ s1,
                   const void* __restrict__ s2, const void* __restrict__ s3,
                   const float* __restrict__ ws, const unsigned short* __restrict__ frow,
                   float* __restrict__ accl, int isb) {
  constexpr int T = cPL[l] + 1;
  constexpr int T2 = T * T;
  const float* U = ws + cUOF[l];
  const void* sps[4] = {s0, s1, s2, s3};
  float rvl[l + 1];
#pragma unroll
  for (int lp = 0; lp <= l; ++lp) rvl[lp] = rrow[cROFF[lp] + cLO[l] + k];

  if constexpr (l == 0) {
    float S = U[0] * ldf(s0, e, isb);
    accl[0] += rvl[0] * S * bu2f(frow[cSOFF[0] + k]);
    return;
  }

  int qc = (k < T2) ? k : 0;
  float S[l + 1];
#pragma unroll
  for (int lp = 0; lp <= l; ++lp) {
    float s = 0.f;
    const void* sp = sps[lp];
#pragma unroll
    for (int mm = 0; mm < 2 * lp + 1; ++mm)
      s += U[qc * T2 + lp * lp + mm] * ldf(sp, (long)e * (2 * lp + 1) + mm, isb);
    S[lp] = s;
  }
  float V[T2];
#pragma unroll
  for (int q = 0; q < T2; ++q) {
    float v = 0.f;
#pragma unroll
    for (int lp = 0; lp <= l; ++lp) v += rvl[lp] * __shfl(S[lp], q, 32);
    V[q] = v;
  }
  float F[T2];
#pragma unroll
  for (int q = 0; q < T2; ++q) F[q] = bu2f(frow[cSOFF[l] + q * 32 + k]);
#pragma unroll
  for (int i = 0; i < T; ++i) {
#pragma unroll
    for (int j = 0; j < T; ++j) {
      float c = 0.f;
#pragma unroll
      for (int t = 0; t < T; ++t) c += V[i * T + t] * F[t * T + j];
      accl[i * T + j] += c;
    }
  }
}

__global__ __launch_bounds__(256) void k_edge3(
    const void* __restrict__ s0, const void* __restrict__ s1,
    const void* __restrict__ s2, const void* __restrict__ s3,
    const int* __restrict__ start, const int* __restrict__ elist,
    const int* __restrict__ neighbors, const int* __restrict__ flag,
    const float* __restrict__ ws, const float* __restrict__ rad,
    const unsigned short* __restrict__ unc, unsigned short* __restrict__ ccg) {
  int a = blockIdx.x;
  int tid = threadIdx.x;
  int wv = tid >> 6;
  int k = tid & 31;
  int strm = tid >> 5;
  int isb = *flag;
  int beg = start[a], end = start[a + 1];

  float acc[44];
#pragma unroll
  for (int j = 0; j < 44; ++j) acc[j] = 0.f;

  for (int i = beg + strm; i < end; i += 8) {
    int e = elist[i];
    int ne = neighbors[e];
    const float* rrow = rad + (size_t)e * 320;
    const unsigned short* frow = unc + (size_t)ne * 1408;
    edge_acc3<0>(e, k, rrow, s0, s1, s2, s3, ws, frow, acc + cAOF[0], isb);
    edge_acc3<1>(e, k, rrow, s0, s1, s2, s3, ws, frow, acc + cAOF[1], isb);
    edge_acc3<2>(e, k, rrow, s0, s1, s2, s3, ws, frow, acc + cAOF[2], isb);
    edge_acc3<3>(e, k, rrow, s0, s1, s2, s3, ws, frow, acc + cAOF[3], isb);
  }
#pragma unroll
  for (int j = 0; j < 44; ++j) acc[j] += __shfl_xor(acc[j], 32);

  __shared__ float buf[4][1408];
  if ((tid & 32) == 0) {
#pragma unroll
    for (int l = 0; l < 4; ++l) {
      int T2 = (cPL[l] + 1) * (cPL[l] + 1);
      for (int q = 0; q < T2; ++q)
        buf[wv][cSOFF[l] + q * 32 + k] = acc[cAOF[l] + q];
    }
  }
  __syncthreads();
  // sum 4 wave-partials into buf[0]
  for (int idx = tid; idx < 1408; idx += 256)
    buf[0][idx] = (buf[0][idx] + buf[1][idx]) + (buf[2][idx] + buf[3][idx]);
  __syncthreads();
  // couple + concat -> ccg (bf16)
  unsigned short* crow = ccg + (size_t)a * 960;
  for (int idx = tid; idx < 960; idx += 256) {
    int kk = idx & 31, combo = idx >> 5;
    int l = c_tl[combo], mm = c_tmm[combo], s = c_ts[combo];
    int lp = l + s;
    int Ts = c_pl_r[lp] + 1;
    int Ts2 = Ts * Ts;
    const float* U = ws + c_uof_r[lp];
    const float* pr = &buf[0][c_soff_r[lp]];
    int m = l * l + mm;
    float sacc = 0.f;
    for (int q = 0; q < Ts2; ++q) sacc += U[q * Ts2 + m] * pr[q * 32 + kk];
    crow[idx] = f2bu(sacc);
  }
}

// ---------------- k_out2: MFMA GEMM  out = feats + concat @ Wl ----------------
template <int l>
DEV void out_body(const void* __restrict__ ft, const void* __restrict__ wl,
                  const unsigned short* __restrict__ ccg, void* __restrict__ out,
                  int rt, int tid, int isb) {
  constexpr int NMM = 2 * l + 1;
  constexpr int K   = cK[l];
  constexpr int NKS = K / 32;
  constexpr int M   = N_ATOMS * NMM;
  constexpr int NET = (l <= 1) ? 4 : (l == 2 ? 2 : 1);
  int wv = tid >> 6, lane = tid & 63;
  int c0, et0;
  bool active = true;
  if constexpr (l == 0)      { c0 = wv * 32;       et0 = 0; }
  else if constexpr (l == 1) { c0 = wv * 32;       et0 = 0; active = (wv < 3); }
  else if constexpr (l == 2) { c0 = (wv & 1) * 32; et0 = (wv >> 1) * 2; }
  else                       { c0 = 0;             et0 = wv; }
  if (!active) return;
  int ln15 = lane & 15, lhi = lane >> 4;
  int r0 = rt * 64;
  // B fragments from Wl (input dtype)
  short8 Bf[2][NKS];
#pragma unroll
  for (int ct = 0; ct < 2; ++ct)
#pragma unroll
    for (int ks = 0; ks < NKS; ++ks) {
      int col = c0 + ct * 16 + ln15;
      int kb  = ks * 32 + lhi * 8;
#pragma unroll
      for (int i = 0; i < 8; ++i)
        Bf[ct][ks][i] = ldb(wl, (long)(kb + i) * K + col, isb);
    }
  // A row bases (concat rows, bf16)
  long abase[NET];
#pragma unroll
  for (int et = 0; et < NET; ++et) {
    int R = r0 + (et0 + et) * 16 + ln15;
    if (R >= M) R = M - 1;
    int a = R / NMM, mm = R - a * NMM;
    abase[et] = (long)a * 960 + cCB[l] + (long)mm * K;
  }
  f32x4 acc[NET][2];
#pragma unroll
  for (int et = 0; et < NET; ++et)
#pragma unroll
    for (int ct = 0; ct < 2; ++ct) acc[et][ct] = (f32x4){0.f, 0.f, 0.f, 0.f};
#pragma unroll
  for (int et = 0; et < NET; ++et) {
#pragma unroll
    for (int ks = 0; ks < NKS; ++ks) {
      short8 Af = *reinterpret_cast<const short8*>(&ccg[abase[et] + ks * 32 + lhi * 8]);
      acc[et][0] = __builtin_amdgcn_mfma_f32_16x16x32_bf16(Af, Bf[0][ks], acc[et][0], 0, 0, 0);
      acc[et][1] = __builtin_amdgcn_mfma_f32_16x16x32_bf16(Af, Bf[1][ks], acc[et][1], 0, 0, 0);
    }
  }
  // C: out = feats + acc;  row R -> flat index R*K + col (row ordering == (a,mm))
#pragma unroll
  for (int et = 0; et < NET; ++et)
#pragma unroll
    for (int ct = 0; ct < 2; ++ct)
#pragma unroll
      for (int r = 0; r < 4; ++r) {
        int R = r0 + (et0 + et) * 16 + lhi * 4 + r;
        if (R < M) {
          int col = c0 + ct * 16 + ln15;
          long o = (long)R * K + col;
          stf(out, cOUT[l] + o, ldf(ft, o, isb) + acc[et][ct][r], isb);
        }
      }
}

__global__ __launch_bounds__(256) void k_out2(
    const void* __restrict__ f0, const void* __restrict__ f1,
    const void* __restrict__ f2, const void* __restrict__ f3,
    const void* __restrict__ wl0, const void* __restrict__ wl1,
    const void* __restrict__ wl2, const void* __restrict__ wl3,
    const int* __restrict__ flag, const unsigned short* __restrict__ ccg,
    void* __restrict__ out) {
  int isb = *flag;
  int b = blockIdx.x;
  int tid = threadIdx.x;
  if      (b < 40)  out_body<0>(f0, wl0, ccg, out, b,       tid, isb);
  else if (b < 158) out_body<1>(f1, wl1, ccg, out, b - 40,  tid, isb);
  else if (b < 354) out_body<2>(f2, wl2, ccg, out, b - 158, tid, isb);
  else              out_body<3>(f3, wl3, ccg, out, b - 354, tid, isb);
}

// ---------------- launch ----------------
extern "C" void kernel_launch(void* const* d_in, const int* in_sizes, int n_in,
                              void* d_out, int out_size, void* d_ws, size_t ws_size,
                              hipStream_t stream) {
  (void)n_in; (void)out_size; (void)ws_size;
  bool dictord = (in_sizes[1] == 40000);
  const void* rb[4]; const void* sph[4]; const void* ft[4];
  const void *w1[4], *w2[4], *wl[4];
  for (int l = 0; l < 4; ++l) {
    if (dictord) {
      rb[l]  = d_in[3 * l + 0];
      sph[l] = d_in[3 * l + 1];
      ft[l]  = d_in[3 * l + 2];
      w1[l]  = d_in[17 + 3 * l];
      w2[l]  = d_in[18 + 3 * l];
      wl[l]  = d_in[19 + 3 * l];
    } else {
      rb[l]  = d_in[l];
      sph[l] = d_in[4 + l];
      ft[l]  = d_in[8 + l];
      w1[l]  = d_in[17 + l];
      w2[l]  = d_in[21 + l];
      wl[l]  = d_in[25 + l];
    }
  }
  const int* centers   = (const int*)d_in[12];
  const int* neighbors = (const int*)d_in[13];
  const void* u0 = d_in[14];
  const void* u2 = d_in[15];
  const void* u4 = d_in[16];

  float* ws   = (float*)d_ws;
  int*   flag = (int*)(ws + FLAG_OFF);
  float* rad  = ws + RAD_OFF;
  unsigned short* unc = (unsigned short*)(ws + UNC_OFF);
  unsigned short* ccg = (unsigned short*)(ws + CCG_OFF);
  int*   cnt   = (int*)(ws + CNT_OFF);
  int*   start = (int*)(ws + START_OFF);
  int*   fill  = (int*)(ws + FILL_OFF);
  int*   elist = (int*)(ws + ELIST_OFF);

  hipMemsetAsync(cnt, 0, N_ATOMS * sizeof(int), stream);
  k_detect<<<1, 64, 0, stream>>>(w2[0], flag);
  k_count<<<(N_EDGES + 255) / 256, 256, 0, stream>>>(centers, cnt);
  k_scan<<<1, 256, 0, stream>>>(cnt, start, fill);
  k_fill<<<(N_EDGES + 255) / 256, 256, 0, stream>>>(centers, fill, elist);
  k_prep<<<208, 256, 0, stream>>>(w1[0], w1[1], w1[2], w1[3],
                                  w2[0], w2[1], w2[2], w2[3],
                                  wl[0], wl[1], wl[2], wl[3],
                                  u0, u2, u4, flag, ws);
  k_radial4<<<2500, 256, 0, stream>>>(rb[0], rb[1], rb[2], rb[3],
                                      w2[0], w2[1], w2[2], w2[3], flag, ws, rad);
  k_uncfeat<<<N_ATOMS / 2, 64, 0, stream>>>(ft[0], ft[1], ft[2], ft[3], flag, ws, unc);
  k_edge3<<<N_ATOMS, 256, 0, stream>>>(sph[0], sph[1], sph[2], sph[3],
                                       start, elist, neighbors, flag, ws, rad, unc, ccg);
  k_out2<<<628, 256, 0, stream>>>(ft[0], ft[1], ft[2], ft[3],
                                  wl[0], wl[1], wl[2], wl[3], flag, ccg, (void*)d_out);
}